// Round 3
// baseline (6799.779 us; speedup 1.0000x reference)
//
#include <hip/hip_runtime.h>
#include <hip/hip_bf16.h>

// Problem constants (hardcoded; H=W=28 scalars in d_in[26..27] ignored)
#define BATCH 32
#define NPOS 784      // 28*28
#define DIM 768
#define HEADS 12
#define HD 64
#define AGENT 49
#define HH 28
#define WW 28
#define MROWS (BATCH*NPOS)   // 25088
#define SCALE 0.125f

using bf16 = __hip_bfloat16;

__device__ __forceinline__ float bf2f(bf16 x) { return __bfloat162float(x); }

// ---------------------------------------------------------------------------
// GEMM: C[M,N](bf16) = A[M,K](f32) @ W[K,N](f32), f32 accumulate
// 128x128 tile, BK=16, 256 threads, 8x8 microtile (cols strided by 16)
// ---------------------------------------------------------------------------
__global__ __launch_bounds__(256) void gemm_f32_bf16(
    const float* __restrict__ A, const float* __restrict__ W,
    bf16* __restrict__ C, int M, int N, int K)
{
    __shared__ float As[16][128];
    __shared__ float Bs[16][128];
    int tid = threadIdx.x;
    int m0 = blockIdx.y * 128, n0 = blockIdx.x * 128;
    int ty = tid >> 4, tx = tid & 15;

    float acc[8][8];
#pragma unroll
    for (int i = 0; i < 8; ++i)
#pragma unroll
        for (int j = 0; j < 8; ++j) acc[i][j] = 0.f;

    int am = tid >> 1, ak = (tid & 1) * 8;
    int bk = tid >> 4, bn = (tid & 15) * 8;

    for (int k0 = 0; k0 < K; k0 += 16) {
        {
            const float* p = A + (size_t)(m0 + am) * K + k0 + ak;
            float4 r0 = *reinterpret_cast<const float4*>(p);
            float4 r1 = *reinterpret_cast<const float4*>(p + 4);
            As[ak + 0][am] = r0.x; As[ak + 1][am] = r0.y;
            As[ak + 2][am] = r0.z; As[ak + 3][am] = r0.w;
            As[ak + 4][am] = r1.x; As[ak + 5][am] = r1.y;
            As[ak + 6][am] = r1.z; As[ak + 7][am] = r1.w;
        }
        {
            const float* p = W + (size_t)(k0 + bk) * N + n0 + bn;
            float4 r0 = *reinterpret_cast<const float4*>(p);
            float4 r1 = *reinterpret_cast<const float4*>(p + 4);
            Bs[bk][bn + 0] = r0.x; Bs[bk][bn + 1] = r0.y;
            Bs[bk][bn + 2] = r0.z; Bs[bk][bn + 3] = r0.w;
            Bs[bk][bn + 4] = r1.x; Bs[bk][bn + 5] = r1.y;
            Bs[bk][bn + 6] = r1.z; Bs[bk][bn + 7] = r1.w;
        }
        __syncthreads();
#pragma unroll
        for (int kk = 0; kk < 16; ++kk) {
            float a[8], bv[8];
#pragma unroll
            for (int i = 0; i < 8; ++i) a[i] = As[kk][ty * 8 + i];
#pragma unroll
            for (int j = 0; j < 8; ++j) bv[j] = Bs[kk][tx + 16 * j];
#pragma unroll
            for (int i = 0; i < 8; ++i)
#pragma unroll
                for (int j = 0; j < 8; ++j) acc[i][j] += a[i] * bv[j];
        }
        __syncthreads();
    }
#pragma unroll
    for (int i = 0; i < 8; ++i) {
        size_t m = m0 + ty * 8 + i;
#pragma unroll
        for (int j = 0; j < 8; ++j) {
            size_t n = n0 + tx + 16 * j;
            C[m * N + n] = __float2bfloat16(acc[i][j]);
        }
    }
}

// ---------------------------------------------------------------------------
// Proj GEMM: C[M,N](f32, ->d_out) = A[M,K](bf16) @ W[K,N](f32) + bias(f32)
// ---------------------------------------------------------------------------
__global__ __launch_bounds__(256) void gemm_proj(
    const bf16* __restrict__ A, const float* __restrict__ W,
    const float* __restrict__ bias, float* __restrict__ C, int M, int N, int K)
{
    __shared__ float As[16][128];
    __shared__ float Bs[16][128];
    int tid = threadIdx.x;
    int m0 = blockIdx.y * 128, n0 = blockIdx.x * 128;
    int ty = tid >> 4, tx = tid & 15;

    float acc[8][8];
#pragma unroll
    for (int i = 0; i < 8; ++i)
#pragma unroll
        for (int j = 0; j < 8; ++j) acc[i][j] = 0.f;

    int am = tid >> 1, ak = (tid & 1) * 8;
    int bk = tid >> 4, bn = (tid & 15) * 8;

    for (int k0 = 0; k0 < K; k0 += 16) {
        {
            const bf16* p = A + (size_t)(m0 + am) * K + k0 + ak;
            int4 raw = *reinterpret_cast<const int4*>(p);
            const bf16* hp = reinterpret_cast<const bf16*>(&raw);
#pragma unroll
            for (int t = 0; t < 8; ++t) As[ak + t][am] = bf2f(hp[t]);
        }
        {
            const float* p = W + (size_t)(k0 + bk) * N + n0 + bn;
            float4 r0 = *reinterpret_cast<const float4*>(p);
            float4 r1 = *reinterpret_cast<const float4*>(p + 4);
            Bs[bk][bn + 0] = r0.x; Bs[bk][bn + 1] = r0.y;
            Bs[bk][bn + 2] = r0.z; Bs[bk][bn + 3] = r0.w;
            Bs[bk][bn + 4] = r1.x; Bs[bk][bn + 5] = r1.y;
            Bs[bk][bn + 6] = r1.z; Bs[bk][bn + 7] = r1.w;
        }
        __syncthreads();
#pragma unroll
        for (int kk = 0; kk < 16; ++kk) {
            float a[8], bv[8];
#pragma unroll
            for (int i = 0; i < 8; ++i) a[i] = As[kk][ty * 8 + i];
#pragma unroll
            for (int j = 0; j < 8; ++j) bv[j] = Bs[kk][tx + 16 * j];
#pragma unroll
            for (int i = 0; i < 8; ++i)
#pragma unroll
                for (int j = 0; j < 8; ++j) acc[i][j] += a[i] * bv[j];
        }
        __syncthreads();
    }
#pragma unroll
    for (int i = 0; i < 8; ++i) {
        size_t m = m0 + ty * 8 + i;
#pragma unroll
        for (int j = 0; j < 8; ++j) {
            size_t n = n0 + tx + 16 * j;
            C[m * N + n] = acc[i][j] + bias[n];
        }
    }
}

// ---------------------------------------------------------------------------
// Pool: ahp[b][a][c] = mean over 4x4 block of q[b][n][c]  (bf16 in, f32 out)
// ---------------------------------------------------------------------------
__global__ void pool_kernel(const bf16* __restrict__ q, float* __restrict__ ahp)
{
    int idx = blockIdx.x * 256 + threadIdx.x;
    if (idx >= BATCH * AGENT * DIM) return;
    int c = idx % DIM;
    int a = (idx / DIM) % AGENT;
    int b = idx / (DIM * AGENT);
    int ai = a / 7, aj = a % 7;
    float s = 0.f;
#pragma unroll
    for (int u = 0; u < 4; ++u)
#pragma unroll
        for (int v = 0; v < 4; ++v) {
            int n = (ai * 4 + u) * WW + (aj * 4 + v);
            s += bf2f(q[((size_t)b * NPOS + n) * DIM + c]);
        }
    ahp[idx] = s * (1.f / 16.f);
}

// ---------------------------------------------------------------------------
// Bilinear 7->28 upsample, half-pixel centers, edge clamp (== jax resize linear)
// ---------------------------------------------------------------------------
__device__ __forceinline__ float bilerp7(const float* __restrict__ img, int i, int j)
{
    float si = 0.25f * i - 0.375f, sj = 0.25f * j - 0.375f;
    int i0 = (int)floorf(si); float fi = si - i0;
    int j0 = (int)floorf(sj); float fj = sj - j0;
    int i0c = min(max(i0, 0), 6), i1c = min(max(i0 + 1, 0), 6);
    int j0c = min(max(j0, 0), 6), j1c = min(max(j0 + 1, 0), 6);
    float v00 = img[i0c * 7 + j0c], v01 = img[i0c * 7 + j1c];
    float v10 = img[i1c * 7 + j0c], v11 = img[i1c * 7 + j1c];
    return (1.f - fi) * ((1.f - fj) * v00 + fj * v01) + fi * ((1.f - fj) * v10 + fj * v11);
}

// pb[h][a][n] = bilerp(an[h][a]) + ah_b[h][a][i] + aw_b[h][a][j]   (f32 in, bf16 out)
__global__ void pos_bias_kernel(const float* __restrict__ an, const float* __restrict__ ah_b,
                                const float* __restrict__ aw_b, bf16* __restrict__ pb)
{
    int idx = blockIdx.x * 256 + threadIdx.x;
    if (idx >= HEADS * AGENT * NPOS) return;
    int n = idx % NPOS;
    int a = (idx / NPOS) % AGENT;
    int h = idx / (NPOS * AGENT);
    int i = n / WW, j = n % WW;
    float v = bilerp7(an + (size_t)(h * AGENT + a) * 49, i, j);
    v += ah_b[(h * AGENT + a) * HH + i] + aw_b[(h * AGENT + a) * WW + j];
    pb[idx] = __float2bfloat16(v);
}

// ab[h][n][a] = bilerp(na[h][a]) + ha_b[h][i][a] + wa_b[h][j][a]   (f32 in, bf16 out)
__global__ void ag_bias_kernel(const float* __restrict__ na, const float* __restrict__ ha_b,
                               const float* __restrict__ wa_b, bf16* __restrict__ ab)
{
    int idx = blockIdx.x * 256 + threadIdx.x;
    if (idx >= HEADS * NPOS * AGENT) return;
    int a = idx % AGENT;
    int n = (idx / AGENT) % NPOS;
    int h = idx / (AGENT * NPOS);
    int i = n / WW, j = n % WW;
    float v = bilerp7(na + (size_t)(h * AGENT + a) * 49, i, j);
    v += ha_b[(h * HH + i) * AGENT + a] + wa_b[(h * WW + j) * AGENT + a];
    ab[idx] = __float2bfloat16(v);
}

// ---------------------------------------------------------------------------
// Agent attention: agent_v[b][h][a][d] = softmax_n(ahp.K^T*scale + pb) @ V
// one block (256 thr) per (b,h,a); kv holds K at col c, V at col 768+c
// ---------------------------------------------------------------------------
__global__ __launch_bounds__(256) void agent_attn(
    const float* __restrict__ ahp, const bf16* __restrict__ kv,
    const bf16* __restrict__ pb, bf16* __restrict__ agent_v)
{
    __shared__ float qs[HD];
    __shared__ float s[NPOS];
    __shared__ float red[256];
    __shared__ float psum[4][HD];
    int tid = threadIdx.x;
    int blk = blockIdx.x;
    int a = blk % AGENT;
    int h = (blk / AGENT) % HEADS;
    int b = blk / (AGENT * HEADS);

    if (tid < HD) qs[tid] = ahp[((size_t)b * AGENT + a) * DIM + h * HD + tid] * SCALE;
    __syncthreads();

    float lmax = -1e30f;
    for (int n = tid; n < NPOS; n += 256) {
        const bf16* kp = kv + ((size_t)(b * NPOS + n)) * (2 * DIM) + h * HD;
        float acc = 0.f;
#pragma unroll
        for (int d = 0; d < HD; d += 8) {
            int4 raw = *reinterpret_cast<const int4*>(kp + d);
            const bf16* hp = reinterpret_cast<const bf16*>(&raw);
#pragma unroll
            for (int t = 0; t < 8; ++t) acc += qs[d + t] * bf2f(hp[t]);
        }
        acc += bf2f(pb[((size_t)h * AGENT + a) * NPOS + n]);
        s[n] = acc;
        lmax = fmaxf(lmax, acc);
    }
    red[tid] = lmax;
    __syncthreads();
    for (int off = 128; off > 0; off >>= 1) {
        if (tid < off) red[tid] = fmaxf(red[tid], red[tid + off]);
        __syncthreads();
    }
    float m = red[0];
    __syncthreads();

    float lsum = 0.f;
    for (int n = tid; n < NPOS; n += 256) {
        float p = __expf(s[n] - m);
        s[n] = p;
        lsum += p;
    }
    red[tid] = lsum;
    __syncthreads();
    for (int off = 128; off > 0; off >>= 1) {
        if (tid < off) red[tid] += red[tid + off];
        __syncthreads();
    }
    float inv = 1.f / red[0];

    int ch = tid >> 6, d = tid & 63;
    float acc = 0.f;
    for (int n = ch * 196; n < (ch + 1) * 196; ++n) {
        acc += s[n] * bf2f(kv[((size_t)(b * NPOS + n)) * (2 * DIM) + DIM + h * HD + d]);
    }
    psum[ch][d] = acc;
    __syncthreads();
    if (tid < HD) {
        float o = (psum[0][tid] + psum[1][tid] + psum[2][tid] + psum[3][tid]) * inv;
        agent_v[(((size_t)b * HEADS + h) * AGENT + a) * HD + tid] = __float2bfloat16(o);
    }
}

// ---------------------------------------------------------------------------
// Q attention + fused depthwise conv, IN-PLACE over q.
// qpre[b][n][h*64+d] read as q, overwritten with
//   softmax_a(q.ah^T*scale + ab) @ agent_v  +  dwc3x3(V_own)[b,n,c] + dwc_b[c]
// block = (b,h,chunk-of-16-n); 4 waves, each wave does 4 n-rows
// ---------------------------------------------------------------------------
__global__ __launch_bounds__(256) void q_attn_dwc(
    bf16* qpre, const bf16* __restrict__ kv_own,
    const float* __restrict__ ahp_x, const bf16* __restrict__ ab_x,
    const bf16* __restrict__ agv_x,
    const float* __restrict__ dwc_w, const float* __restrict__ dwc_b)
{
    __shared__ float ahS[64 * 65];   // padded stride 65; rows 49..63 zero
    __shared__ float avS[AGENT * HD];
    int tid = threadIdx.x;
    int blk = blockIdx.x;
    int chunk = blk % 49;
    int h = (blk / 49) % HEADS;
    int b = blk / (49 * HEADS);

    for (int i = tid; i < 64 * 65; i += 256) {
        int a = i / 65, d = i % 65;
        float v = 0.f;
        if (a < AGENT && d < HD)
            v = ahp_x[((size_t)b * AGENT + a) * DIM + h * HD + d];
        ahS[i] = v;
    }
    for (int i = tid; i < AGENT * HD; i += 256) {
        int a = i >> 6, d = i & 63;
        avS[i] = bf2f(agv_x[(((size_t)b * HEADS + h) * AGENT + a) * HD + d]);
    }
    __syncthreads();

    int wave = tid >> 6, lane = tid & 63;
    int c = h * HD + lane;
    // hoist depthwise weights + bias for this channel
    float wv[9];
#pragma unroll
    for (int t = 0; t < 9; ++t) wv[t] = dwc_w[t * DIM + c];
    float cb = dwc_b[c];

#pragma unroll
    for (int r = 0; r < 4; ++r) {
        int n = chunk * 16 + wave * 4 + r;
        int i = n / WW, j = n % WW;
        size_t qidx = ((size_t)(b * NPOS + n)) * DIM + c;
        float qd = bf2f(qpre[qidx]);
        float acc = 0.f;
#pragma unroll
        for (int d = 0; d < HD; ++d)
            acc += __shfl(qd, d) * ahS[lane * 65 + d];
        float sa = (lane < AGENT)
                       ? (acc * SCALE + bf2f(ab_x[((size_t)h * NPOS + n) * AGENT + lane]))
                       : -1e30f;
        float mx = sa;
#pragma unroll
        for (int off = 32; off > 0; off >>= 1) mx = fmaxf(mx, __shfl_xor(mx, off));
        float p = (lane < AGENT) ? __expf(sa - mx) : 0.f;
        float sm = p;
#pragma unroll
        for (int off = 32; off > 0; off >>= 1) sm += __shfl_xor(sm, off);
        p /= sm;
        float o = 0.f;
#pragma unroll
        for (int a = 0; a < AGENT; ++a)
            o += __shfl(p, a) * avS[a * HD + lane];

        // fused depthwise 3x3 over own-modality V (cols 768.. of kv_own)
        float conv = cb;
#pragma unroll
        for (int di = -1; di <= 1; ++di) {
            int ii = i + di;
            if (ii < 0 || ii >= HH) continue;
#pragma unroll
            for (int dj = -1; dj <= 1; ++dj) {
                int jj = j + dj;
                if (jj < 0 || jj >= WW) continue;
                conv += wv[(di + 1) * 3 + (dj + 1)] *
                        bf2f(kv_own[((size_t)(b * NPOS + ii * WW + jj)) * (2 * DIM) + DIM + c]);
            }
        }
        qpre[qidx] = __float2bfloat16(o + conv);
    }
}

// ---------------------------------------------------------------------------
extern "C" void kernel_launch(void* const* d_in, const int* in_sizes, int n_in,
                              void* d_out, int out_size, void* d_ws, size_t ws_size,
                              hipStream_t stream)
{
    const float* rgb_fea    = (const float*)d_in[0];
    const float* depth_fea  = (const float*)d_in[1];
    const float* rgb_q_w    = (const float*)d_in[2];
    const float* rgb_kv_w   = (const float*)d_in[3];
    const float* rgb_proj_w = (const float*)d_in[4];
    const float* rgb_proj_b = (const float*)d_in[5];
    const float* depth_q_w    = (const float*)d_in[6];
    const float* depth_kv_w   = (const float*)d_in[7];
    const float* depth_proj_w = (const float*)d_in[8];
    const float* depth_proj_b = (const float*)d_in[9];
    const float* rgb_dwc_w   = (const float*)d_in[10];
    const float* rgb_dwc_b   = (const float*)d_in[11];
    const float* depth_dwc_w = (const float*)d_in[12];
    const float* depth_dwc_b = (const float*)d_in[13];
    const float* rgb_an   = (const float*)d_in[14];
    const float* rgb_na   = (const float*)d_in[15];
    const float* rgb_ah_b = (const float*)d_in[16];
    const float* rgb_aw_b = (const float*)d_in[17];
    const float* rgb_ha_b = (const float*)d_in[18];
    const float* rgb_wa_b = (const float*)d_in[19];
    const float* depth_an   = (const float*)d_in[20];
    const float* depth_na   = (const float*)d_in[21];
    const float* depth_ah_b = (const float*)d_in[22];
    const float* depth_aw_b = (const float*)d_in[23];
    const float* depth_ha_b = (const float*)d_in[24];
    const float* depth_wa_b = (const float*)d_in[25];

    char* ws = (char*)d_ws;
    size_t off = 0;
    auto alloc = [&](size_t bytes) -> void* {
        void* p = ws + off;
        off += (bytes + 255) & ~(size_t)255;
        return p;
    };
    // Total ws usage ~245 MB
    bf16* rgb_q    = (bf16*)alloc((size_t)MROWS * DIM * 2);       // doubles as rgb_pre
    bf16* depth_q  = (bf16*)alloc((size_t)MROWS * DIM * 2);       // doubles as depth_pre
    bf16* rgb_kv   = (bf16*)alloc((size_t)MROWS * 2 * DIM * 2);
    bf16* depth_kv = (bf16*)alloc((size_t)MROWS * 2 * DIM * 2);
    float* rgb_ahp   = (float*)alloc((size_t)BATCH * AGENT * DIM * 4);
    float* depth_ahp = (float*)alloc((size_t)BATCH * AGENT * DIM * 4);
    bf16* rgb_pb    = (bf16*)alloc((size_t)HEADS * AGENT * NPOS * 2);
    bf16* depth_pb  = (bf16*)alloc((size_t)HEADS * AGENT * NPOS * 2);
    bf16* rgb_ab    = (bf16*)alloc((size_t)HEADS * NPOS * AGENT * 2);
    bf16* depth_ab  = (bf16*)alloc((size_t)HEADS * NPOS * AGENT * 2);
    bf16* rgb_agv   = (bf16*)alloc((size_t)BATCH * HEADS * AGENT * HD * 2);
    bf16* depth_agv = (bf16*)alloc((size_t)BATCH * HEADS * AGENT * HD * 2);

    dim3 blk(256);

    // 1) q / kv projections (f32 inputs -> bf16 intermediates)
    gemm_f32_bf16<<<dim3(6, 196), blk, 0, stream>>>(rgb_fea, rgb_q_w, rgb_q, MROWS, DIM, DIM);
    gemm_f32_bf16<<<dim3(6, 196), blk, 0, stream>>>(depth_fea, depth_q_w, depth_q, MROWS, DIM, DIM);
    gemm_f32_bf16<<<dim3(12, 196), blk, 0, stream>>>(rgb_fea, rgb_kv_w, rgb_kv, MROWS, 2 * DIM, DIM);
    gemm_f32_bf16<<<dim3(12, 196), blk, 0, stream>>>(depth_fea, depth_kv_w, depth_kv, MROWS, 2 * DIM, DIM);

    // 2) agent pooling of q
    pool_kernel<<<(BATCH * AGENT * DIM + 255) / 256, blk, 0, stream>>>(rgb_q, rgb_ahp);
    pool_kernel<<<(BATCH * AGENT * DIM + 255) / 256, blk, 0, stream>>>(depth_q, depth_ahp);

    // 3) position biases
    pos_bias_kernel<<<(HEADS * AGENT * NPOS + 255) / 256, blk, 0, stream>>>(rgb_an, rgb_ah_b, rgb_aw_b, rgb_pb);
    pos_bias_kernel<<<(HEADS * AGENT * NPOS + 255) / 256, blk, 0, stream>>>(depth_an, depth_ah_b, depth_aw_b, depth_pb);
    ag_bias_kernel<<<(HEADS * NPOS * AGENT + 255) / 256, blk, 0, stream>>>(rgb_na, rgb_ha_b, rgb_wa_b, rgb_ab);
    ag_bias_kernel<<<(HEADS * NPOS * AGENT + 255) / 256, blk, 0, stream>>>(depth_na, depth_ha_b, depth_wa_b, depth_ab);

    // 4) cross-modal agent aggregation
    // depth agents attend rgb k/v (bias rgb_pb) -> depth_agv
    agent_attn<<<BATCH * HEADS * AGENT, blk, 0, stream>>>(depth_ahp, rgb_kv, rgb_pb, depth_agv);
    // rgb agents attend depth k/v (bias depth_pb) -> rgb_agv
    agent_attn<<<BATCH * HEADS * AGENT, blk, 0, stream>>>(rgb_ahp, depth_kv, depth_pb, rgb_agv);

    // 5) agent broadcast + fused own-modality depthwise conv (in-place q -> pre)
    q_attn_dwc<<<BATCH * HEADS * 49, blk, 0, stream>>>(rgb_q, rgb_kv, depth_ahp, depth_ab, depth_agv,
                                                       rgb_dwc_w, rgb_dwc_b);
    q_attn_dwc<<<BATCH * HEADS * 49, blk, 0, stream>>>(depth_q, depth_kv, rgb_ahp, rgb_ab, rgb_agv,
                                                       depth_dwc_w, depth_dwc_b);

    // 6) output projections (f32 out to d_out)
    float* out = (float*)d_out;
    gemm_proj<<<dim3(6, 196), blk, 0, stream>>>(rgb_q, rgb_proj_w, rgb_proj_b, out, MROWS, DIM, DIM);
    gemm_proj<<<dim3(6, 196), blk, 0, stream>>>(depth_q, depth_proj_w, depth_proj_b,
                                                out + (size_t)MROWS * DIM, MROWS, DIM, DIM);
}

// Round 4
// 3340.072 us; speedup vs baseline: 2.0358x; 2.0358x over previous
//
#include <hip/hip_runtime.h>
#include <hip/hip_bf16.h>

#define BATCH 32
#define NPOS 784
#define DIM 768
#define HEADS 12
#define HD 64
#define AGENT 49
#define HH 28
#define WW 28
#define MROWS (BATCH*NPOS)   // 25088
#define SCALE 0.125f

using bf16 = __hip_bfloat16;
typedef __attribute__((ext_vector_type(4))) float f32x4;
typedef __attribute__((ext_vector_type(8))) short short8v;

__device__ __forceinline__ float bf2f(bf16 x) { return __bfloat162float(x); }
__device__ __forceinline__ unsigned short f2bf(float x) {
    unsigned int u = __float_as_uint(x);
    unsigned int r = (u + 0x7fffu + ((u >> 16) & 1u)) >> 16;
    return (unsigned short)r;
}

// ---------------------------------------------------------------------------
// Transpose+convert: W [K][N] f32 -> Wt [N][K] bf16. 256 thr = 32x8.
// ---------------------------------------------------------------------------
__global__ __launch_bounds__(256) void transpose_w_bf16(
    const float* __restrict__ W, bf16* __restrict__ Wt, int K, int N)
{
    __shared__ float t[32][33];
    int tx = threadIdx.x & 31, ty = threadIdx.x >> 5;
    int k0 = blockIdx.y * 32, n0 = blockIdx.x * 32;
#pragma unroll
    for (int i = 0; i < 4; ++i)
        t[ty + 8 * i][tx] = W[(size_t)(k0 + ty + 8 * i) * N + n0 + tx];
    __syncthreads();
#pragma unroll
    for (int i = 0; i < 4; ++i)
        Wt[(size_t)(n0 + ty + 8 * i) * K + k0 + tx] = __float2bfloat16(t[tx][ty + 8 * i]);
}

// ---------------------------------------------------------------------------
// MFMA GEMM: C[M,N] = A[M,K] @ Bt[N,K]^T, bf16 MFMA, f32 accum.
// A is f32 (converted in staging) or bf16; C is bf16 or f32(+bias).
// 128x128 tile, BK=32, 256 thr = 4 waves (2x2 of 64x64), 4x4 16x16x32 frags.
// LDS rows padded to 40 bf16 (80 B) -> 2-way max bank aliasing (free).
// ---------------------------------------------------------------------------
template<bool AF32, bool OUTF32>
__global__ __launch_bounds__(256) void gemm_mfma(
    const void* __restrict__ Ap, const bf16* __restrict__ Bt,
    const float* __restrict__ bias, void* __restrict__ Cp,
    int M, int N, int K)
{
    __shared__ short As[128][40];
    __shared__ short Bs[128][40];
    int tid = threadIdx.x;
    int wave = tid >> 6, lane = tid & 63;
    int m0 = blockIdx.y * 128, n0 = blockIdx.x * 128;
    int wm = (wave >> 1) * 64, wn = (wave & 1) * 64;

    f32x4 acc[4][4] = {};

    const short* Ab = (const short*)Ap;
    const float* Af = (const float*)Ap;
    const short* Btb = (const short*)Bt;

    for (int k0 = 0; k0 < K; k0 += 32) {
        if constexpr (AF32) {
#pragma unroll
            for (int it = 0; it < 4; ++it) {
                int idx = tid + 256 * it;            // 1024 float4 chunks
                int row = idx >> 3, kp = (idx & 7) * 4;
                float4 v = *reinterpret_cast<const float4*>(
                    Af + (size_t)(m0 + row) * K + k0 + kp);
                unsigned int w0 = (unsigned int)f2bf(v.x) | ((unsigned int)f2bf(v.y) << 16);
                unsigned int w1 = (unsigned int)f2bf(v.z) | ((unsigned int)f2bf(v.w) << 16);
                uint2 pk; pk.x = w0; pk.y = w1;
                *reinterpret_cast<uint2*>(&As[row][kp]) = pk;
            }
        } else {
#pragma unroll
            for (int it = 0; it < 2; ++it) {
                int idx = tid + 256 * it;            // 512 short8 chunks
                int row = idx >> 2, kp = (idx & 3) * 8;
                short8v v = *reinterpret_cast<const short8v*>(
                    Ab + (size_t)(m0 + row) * K + k0 + kp);
                *reinterpret_cast<short8v*>(&As[row][kp]) = v;
            }
        }
#pragma unroll
        for (int it = 0; it < 2; ++it) {
            int idx = tid + 256 * it;
            int row = idx >> 2, kp = (idx & 3) * 8;
            short8v v = *reinterpret_cast<const short8v*>(
                Btb + (size_t)(n0 + row) * K + k0 + kp);
            *reinterpret_cast<short8v*>(&Bs[row][kp]) = v;
        }
        __syncthreads();

        short8v af[4], bfr[4];
#pragma unroll
        for (int mf = 0; mf < 4; ++mf)
            af[mf] = *reinterpret_cast<const short8v*>(
                &As[wm + mf * 16 + (lane & 15)][(lane >> 4) * 8]);
#pragma unroll
        for (int nf = 0; nf < 4; ++nf)
            bfr[nf] = *reinterpret_cast<const short8v*>(
                &Bs[wn + nf * 16 + (lane & 15)][(lane >> 4) * 8]);
#pragma unroll
        for (int mf = 0; mf < 4; ++mf)
#pragma unroll
            for (int nf = 0; nf < 4; ++nf)
                acc[mf][nf] = __builtin_amdgcn_mfma_f32_16x16x32_bf16(
                    af[mf], bfr[nf], acc[mf][nf], 0, 0, 0);
        __syncthreads();
    }

    int rgrp = (lane >> 4) * 4, cidx = lane & 15;
#pragma unroll
    for (int mf = 0; mf < 4; ++mf)
#pragma unroll
        for (int nf = 0; nf < 4; ++nf)
#pragma unroll
            for (int r = 0; r < 4; ++r) {
                int row = m0 + wm + mf * 16 + rgrp + r;
                int col = n0 + wn + nf * 16 + cidx;
                float v = acc[mf][nf][r];
                if constexpr (OUTF32)
                    ((float*)Cp)[(size_t)row * N + col] = v + bias[col];
                else
                    ((bf16*)Cp)[(size_t)row * N + col] = __float2bfloat16(v);
            }
}

// ---------------------------------------------------------------------------
// Pool: ahp[b][a][c] = mean over 4x4 block of q[b][n][c]  (bf16 in, f32 out)
// ---------------------------------------------------------------------------
__global__ void pool_kernel(const bf16* __restrict__ q, float* __restrict__ ahp)
{
    int idx = blockIdx.x * 256 + threadIdx.x;
    if (idx >= BATCH * AGENT * DIM) return;
    int c = idx % DIM;
    int a = (idx / DIM) % AGENT;
    int b = idx / (DIM * AGENT);
    int ai = a / 7, aj = a % 7;
    float s = 0.f;
#pragma unroll
    for (int u = 0; u < 4; ++u)
#pragma unroll
        for (int v = 0; v < 4; ++v) {
            int n = (ai * 4 + u) * WW + (aj * 4 + v);
            s += bf2f(q[((size_t)b * NPOS + n) * DIM + c]);
        }
    ahp[idx] = s * (1.f / 16.f);
}

// ---------------------------------------------------------------------------
// Bilinear 7->28 upsample, half-pixel centers, edge clamp
// ---------------------------------------------------------------------------
__device__ __forceinline__ float bilerp7(const float* __restrict__ img, int i, int j)
{
    float si = 0.25f * i - 0.375f, sj = 0.25f * j - 0.375f;
    int i0 = (int)floorf(si); float fi = si - i0;
    int j0 = (int)floorf(sj); float fj = sj - j0;
    int i0c = min(max(i0, 0), 6), i1c = min(max(i0 + 1, 0), 6);
    int j0c = min(max(j0, 0), 6), j1c = min(max(j0 + 1, 0), 6);
    float v00 = img[i0c * 7 + j0c], v01 = img[i0c * 7 + j1c];
    float v10 = img[i1c * 7 + j0c], v11 = img[i1c * 7 + j1c];
    return (1.f - fi) * ((1.f - fj) * v00 + fj * v01) + fi * ((1.f - fj) * v10 + fj * v11);
}

__global__ void pos_bias_kernel(const float* __restrict__ an, const float* __restrict__ ah_b,
                                const float* __restrict__ aw_b, bf16* __restrict__ pb)
{
    int idx = blockIdx.x * 256 + threadIdx.x;
    if (idx >= HEADS * AGENT * NPOS) return;
    int n = idx % NPOS;
    int a = (idx / NPOS) % AGENT;
    int h = idx / (NPOS * AGENT);
    int i = n / WW, j = n % WW;
    float v = bilerp7(an + (size_t)(h * AGENT + a) * 49, i, j);
    v += ah_b[(h * AGENT + a) * HH + i] + aw_b[(h * AGENT + a) * WW + j];
    pb[idx] = __float2bfloat16(v);
}

__global__ void ag_bias_kernel(const float* __restrict__ na, const float* __restrict__ ha_b,
                               const float* __restrict__ wa_b, bf16* __restrict__ ab)
{
    int idx = blockIdx.x * 256 + threadIdx.x;
    if (idx >= HEADS * NPOS * AGENT) return;
    int a = idx % AGENT;
    int n = (idx / AGENT) % NPOS;
    int h = idx / (AGENT * NPOS);
    int i = n / WW, j = n % WW;
    float v = bilerp7(na + (size_t)(h * AGENT + a) * 49, i, j);
    v += ha_b[(h * HH + i) * AGENT + a] + wa_b[(h * WW + j) * AGENT + a];
    ab[idx] = __float2bfloat16(v);
}

// ---------------------------------------------------------------------------
// Agent attention: agent_v[b][h][a][d] = softmax_n(ahp.K^T*scale + pb) @ V
// ---------------------------------------------------------------------------
__global__ __launch_bounds__(256) void agent_attn(
    const float* __restrict__ ahp, const bf16* __restrict__ kv,
    const bf16* __restrict__ pb, bf16* __restrict__ agent_v)
{
    __shared__ float qs[HD];
    __shared__ float s[NPOS];
    __shared__ float red[256];
    __shared__ float psum[4][HD];
    int tid = threadIdx.x;
    int blk = blockIdx.x;
    int a = blk % AGENT;
    int h = (blk / AGENT) % HEADS;
    int b = blk / (AGENT * HEADS);

    if (tid < HD) qs[tid] = ahp[((size_t)b * AGENT + a) * DIM + h * HD + tid] * SCALE;
    __syncthreads();

    float lmax = -1e30f;
    for (int n = tid; n < NPOS; n += 256) {
        const bf16* kp = kv + ((size_t)(b * NPOS + n)) * (2 * DIM) + h * HD;
        float acc = 0.f;
#pragma unroll
        for (int d = 0; d < HD; d += 8) {
            int4 raw = *reinterpret_cast<const int4*>(kp + d);
            const bf16* hp = reinterpret_cast<const bf16*>(&raw);
#pragma unroll
            for (int t = 0; t < 8; ++t) acc += qs[d + t] * bf2f(hp[t]);
        }
        acc += bf2f(pb[((size_t)h * AGENT + a) * NPOS + n]);
        s[n] = acc;
        lmax = fmaxf(lmax, acc);
    }
    red[tid] = lmax;
    __syncthreads();
    for (int off = 128; off > 0; off >>= 1) {
        if (tid < off) red[tid] = fmaxf(red[tid], red[tid + off]);
        __syncthreads();
    }
    float m = red[0];
    __syncthreads();

    float lsum = 0.f;
    for (int n = tid; n < NPOS; n += 256) {
        float p = __expf(s[n] - m);
        s[n] = p;
        lsum += p;
    }
    red[tid] = lsum;
    __syncthreads();
    for (int off = 128; off > 0; off >>= 1) {
        if (tid < off) red[tid] += red[tid + off];
        __syncthreads();
    }
    float inv = 1.f / red[0];

    int ch = tid >> 6, d = tid & 63;
    float acc = 0.f;
    for (int n = ch * 196; n < (ch + 1) * 196; ++n) {
        acc += s[n] * bf2f(kv[((size_t)(b * NPOS + n)) * (2 * DIM) + DIM + h * HD + d]);
    }
    psum[ch][d] = acc;
    __syncthreads();
    if (tid < HD) {
        float o = (psum[0][tid] + psum[1][tid] + psum[2][tid] + psum[3][tid]) * inv;
        agent_v[(((size_t)b * HEADS + h) * AGENT + a) * HD + tid] = __float2bfloat16(o);
    }
}

// ---------------------------------------------------------------------------
// Q attention + fused depthwise conv, IN-PLACE over q. Shuffle-free.
// S phase: lane=agent, conflict-free ahT[d][a] reads, wave-uniform q loads.
// PV phase: lane=d, pS broadcast + conflict-free avS[a][d] reads.
// block = (b,h,chunk of 16 rows); wave w owns rows w*4..w*4+3.
// ---------------------------------------------------------------------------
__global__ __launch_bounds__(256) void q_attn_dwc2(
    bf16* qpre, const bf16* __restrict__ kv_own,
    const float* __restrict__ ahp_x, const bf16* __restrict__ ab_x,
    const bf16* __restrict__ agv_x,
    const float* __restrict__ dwc_w, const float* __restrict__ dwc_b)
{
    __shared__ float ahT[64][65];   // [d][a], padded; a>=49 zero
    __shared__ float avS[AGENT][64];
    __shared__ float pS[16][64];
    int tid = threadIdx.x;
    int blk = blockIdx.x;
    int chunk = blk % 49;
    int h = (blk / 49) % HEADS;
    int b = blk / (49 * HEADS);

    for (int i = tid; i < 64 * 64; i += 256) {
        int a = i >> 6, d = i & 63;
        ahT[d][a] = (a < AGENT) ? ahp_x[((size_t)b * AGENT + a) * DIM + h * HD + d] : 0.f;
    }
    for (int i = tid; i < AGENT * 64; i += 256) {
        int a = i >> 6, d = i & 63;
        avS[a][d] = bf2f(agv_x[(((size_t)b * HEADS + h) * AGENT + a) * HD + d]);
    }
    __syncthreads();

    int wave = tid >> 6, lane = tid & 63;
    int c = h * HD + lane;
    float wv[9];
#pragma unroll
    for (int t = 0; t < 9; ++t) wv[t] = dwc_w[t * DIM + c];
    float cb = dwc_b[c];

#pragma unroll
    for (int r = 0; r < 4; ++r) {
        int rl = wave * 4 + r;
        int n = chunk * 16 + rl;
        const unsigned int* q32 =
            (const unsigned int*)(qpre + (size_t)(b * NPOS + n) * DIM + h * HD);
        float acc = 0.f;
#pragma unroll
        for (int dp = 0; dp < 32; ++dp) {
            unsigned int u = q32[dp];                 // wave-uniform load
            float qlo = __uint_as_float(u << 16);
            float qhi = __uint_as_float(u & 0xffff0000u);
            acc += qlo * ahT[2 * dp][lane] + qhi * ahT[2 * dp + 1][lane];
        }
        float sa = (lane < AGENT)
                       ? (acc * SCALE + bf2f(ab_x[((size_t)h * NPOS + n) * AGENT + lane]))
                       : -1e30f;
        float mx = sa;
#pragma unroll
        for (int off = 32; off > 0; off >>= 1) mx = fmaxf(mx, __shfl_xor(mx, off));
        float p = (lane < AGENT) ? __expf(sa - mx) : 0.f;
        float sm = p;
#pragma unroll
        for (int off = 32; off > 0; off >>= 1) sm += __shfl_xor(sm, off);
        pS[rl][lane] = p / sm;
    }
    // no barrier needed: each wave reads only its own pS rows

#pragma unroll
    for (int r = 0; r < 4; ++r) {
        int rl = wave * 4 + r;
        int n = chunk * 16 + rl;
        int i = n / WW, j = n % WW;
        float o = 0.f;
#pragma unroll
        for (int a = 0; a < AGENT; ++a)
            o += pS[rl][a] * avS[a][lane];

        float conv = cb;
#pragma unroll
        for (int di = -1; di <= 1; ++di) {
            int ii = i + di;
            if (ii < 0 || ii >= HH) continue;
#pragma unroll
            for (int dj = -1; dj <= 1; ++dj) {
                int jj = j + dj;
                if (jj < 0 || jj >= WW) continue;
                conv += wv[(di + 1) * 3 + (dj + 1)] *
                        bf2f(kv_own[((size_t)(b * NPOS + ii * WW + jj)) * (2 * DIM) + DIM + c]);
            }
        }
        qpre[(size_t)(b * NPOS + n) * DIM + c] = __float2bfloat16(o + conv);
    }
}

// ---------------------------------------------------------------------------
extern "C" void kernel_launch(void* const* d_in, const int* in_sizes, int n_in,
                              void* d_out, int out_size, void* d_ws, size_t ws_size,
                              hipStream_t stream)
{
    const float* rgb_fea    = (const float*)d_in[0];
    const float* depth_fea  = (const float*)d_in[1];
    const float* rgb_q_w    = (const float*)d_in[2];
    const float* rgb_kv_w   = (const float*)d_in[3];
    const float* rgb_proj_w = (const float*)d_in[4];
    const float* rgb_proj_b = (const float*)d_in[5];
    const float* depth_q_w    = (const float*)d_in[6];
    const float* depth_kv_w   = (const float*)d_in[7];
    const float* depth_proj_w = (const float*)d_in[8];
    const float* depth_proj_b = (const float*)d_in[9];
    const float* rgb_dwc_w   = (const float*)d_in[10];
    const float* rgb_dwc_b   = (const float*)d_in[11];
    const float* depth_dwc_w = (const float*)d_in[12];
    const float* depth_dwc_b = (const float*)d_in[13];
    const float* rgb_an   = (const float*)d_in[14];
    const float* rgb_na   = (const float*)d_in[15];
    const float* rgb_ah_b = (const float*)d_in[16];
    const float* rgb_aw_b = (const float*)d_in[17];
    const float* rgb_ha_b = (const float*)d_in[18];
    const float* rgb_wa_b = (const float*)d_in[19];
    const float* depth_an   = (const float*)d_in[20];
    const float* depth_na   = (const float*)d_in[21];
    const float* depth_ah_b = (const float*)d_in[22];
    const float* depth_aw_b = (const float*)d_in[23];
    const float* depth_ha_b = (const float*)d_in[24];
    const float* depth_wa_b = (const float*)d_in[25];

    char* ws = (char*)d_ws;
    size_t off = 0;
    auto alloc = [&](size_t bytes) -> void* {
        void* p = ws + off;
        off += (bytes + 255) & ~(size_t)255;
        return p;
    };
    // persistent (~242 MB)
    bf16* rgb_q    = (bf16*)alloc((size_t)MROWS * DIM * 2);
    bf16* depth_q  = (bf16*)alloc((size_t)MROWS * DIM * 2);
    bf16* rgb_kv   = (bf16*)alloc((size_t)MROWS * 2 * DIM * 2);
    bf16* depth_kv = (bf16*)alloc((size_t)MROWS * 2 * DIM * 2);
    bf16* rgb_pb    = (bf16*)alloc((size_t)HEADS * AGENT * NPOS * 2);
    bf16* depth_pb  = (bf16*)alloc((size_t)HEADS * AGENT * NPOS * 2);
    bf16* rgb_ab    = (bf16*)alloc((size_t)HEADS * NPOS * AGENT * 2);
    bf16* depth_ab  = (bf16*)alloc((size_t)HEADS * NPOS * AGENT * 2);
    bf16* rgb_agv   = (bf16*)alloc((size_t)BATCH * HEADS * AGENT * HD * 2);
    bf16* depth_agv = (bf16*)alloc((size_t)BATCH * HEADS * AGENT * HD * 2);
    bf16* proj_wt_r = (bf16*)alloc((size_t)DIM * DIM * 2);
    bf16* proj_wt_d = (bf16*)alloc((size_t)DIM * DIM * 2);
    // union region (~9.7 MB): {q_wt, kv_wt} dead before {ahp} written
    size_t ubase = off;
    bf16* q_wt_r  = (bf16*)alloc((size_t)DIM * DIM * 2);
    bf16* kv_wt_r = (bf16*)alloc((size_t)DIM * 2 * DIM * 2);
    bf16* q_wt_d  = (bf16*)alloc((size_t)DIM * DIM * 2);
    bf16* kv_wt_d = (bf16*)alloc((size_t)DIM * 2 * DIM * 2);
    off = ubase;  // alias
    float* rgb_ahp   = (float*)alloc((size_t)BATCH * AGENT * DIM * 4);
    float* depth_ahp = (float*)alloc((size_t)BATCH * AGENT * DIM * 4);

    dim3 blk(256);

    // 0) weight transposes (f32 [K][N] -> bf16 [N][K])
    transpose_w_bf16<<<dim3(24, 24), blk, 0, stream>>>(rgb_q_w, q_wt_r, DIM, DIM);
    transpose_w_bf16<<<dim3(48, 24), blk, 0, stream>>>(rgb_kv_w, kv_wt_r, DIM, 2 * DIM);
    transpose_w_bf16<<<dim3(24, 24), blk, 0, stream>>>(depth_q_w, q_wt_d, DIM, DIM);
    transpose_w_bf16<<<dim3(48, 24), blk, 0, stream>>>(depth_kv_w, kv_wt_d, DIM, 2 * DIM);
    transpose_w_bf16<<<dim3(24, 24), blk, 0, stream>>>(rgb_proj_w, proj_wt_r, DIM, DIM);
    transpose_w_bf16<<<dim3(24, 24), blk, 0, stream>>>(depth_proj_w, proj_wt_d, DIM, DIM);

    // 1) q / kv projections (MFMA; f32 A converted in staging)
    gemm_mfma<true, false><<<dim3(6, 196), blk, 0, stream>>>(rgb_fea, q_wt_r, nullptr, rgb_q, MROWS, DIM, DIM);
    gemm_mfma<true, false><<<dim3(6, 196), blk, 0, stream>>>(depth_fea, q_wt_d, nullptr, depth_q, MROWS, DIM, DIM);
    gemm_mfma<true, false><<<dim3(12, 196), blk, 0, stream>>>(rgb_fea, kv_wt_r, nullptr, rgb_kv, MROWS, 2 * DIM, DIM);
    gemm_mfma<true, false><<<dim3(12, 196), blk, 0, stream>>>(depth_fea, kv_wt_d, nullptr, depth_kv, MROWS, 2 * DIM, DIM);

    // 2) agent pooling of q (writes ahp over dead q_wt/kv_wt region)
    pool_kernel<<<(BATCH * AGENT * DIM + 255) / 256, blk, 0, stream>>>(rgb_q, rgb_ahp);
    pool_kernel<<<(BATCH * AGENT * DIM + 255) / 256, blk, 0, stream>>>(depth_q, depth_ahp);

    // 3) position biases
    pos_bias_kernel<<<(HEADS * AGENT * NPOS + 255) / 256, blk, 0, stream>>>(rgb_an, rgb_ah_b, rgb_aw_b, rgb_pb);
    pos_bias_kernel<<<(HEADS * AGENT * NPOS + 255) / 256, blk, 0, stream>>>(depth_an, depth_ah_b, depth_aw_b, depth_pb);
    ag_bias_kernel<<<(HEADS * NPOS * AGENT + 255) / 256, blk, 0, stream>>>(rgb_na, rgb_ha_b, rgb_wa_b, rgb_ab);
    ag_bias_kernel<<<(HEADS * NPOS * AGENT + 255) / 256, blk, 0, stream>>>(depth_na, depth_ha_b, depth_wa_b, depth_ab);

    // 4) cross-modal agent aggregation
    agent_attn<<<BATCH * HEADS * AGENT, blk, 0, stream>>>(depth_ahp, rgb_kv, rgb_pb, depth_agv);
    agent_attn<<<BATCH * HEADS * AGENT, blk, 0, stream>>>(rgb_ahp, depth_kv, depth_pb, rgb_agv);

    // 5) agent broadcast + fused depthwise conv (in-place q -> pre)
    q_attn_dwc2<<<BATCH * HEADS * 49, blk, 0, stream>>>(rgb_q, rgb_kv, depth_ahp, depth_ab, depth_agv,
                                                        rgb_dwc_w, rgb_dwc_b);
    q_attn_dwc2<<<BATCH * HEADS * 49, blk, 0, stream>>>(depth_q, depth_kv, rgb_ahp, rgb_ab, rgb_agv,
                                                        depth_dwc_w, depth_dwc_b);

    // 6) output projections (MFMA, bf16 A, f32 out + bias)
    float* out = (float*)d_out;
    gemm_mfma<false, true><<<dim3(6, 196), blk, 0, stream>>>(rgb_q, proj_wt_r, rgb_proj_b, out, MROWS, DIM, DIM);
    gemm_mfma<false, true><<<dim3(6, 196), blk, 0, stream>>>(depth_q, proj_wt_d, depth_proj_b,
                                                             out + (size_t)MROWS * DIM, MROWS, DIM, DIM);
}

// Round 5
// 2327.127 us; speedup vs baseline: 2.9220x; 1.4353x over previous
//
#include <hip/hip_runtime.h>
#include <hip/hip_bf16.h>

#define BATCH 32
#define NPOS 784
#define DIM 768
#define HEADS 12
#define HD 64
#define AGENT 49
#define HH 28
#define WW 28
#define MROWS (BATCH*NPOS)   // 25088
#define SCALE 0.125f
#define NT 112               // 784 = 7*112, agent-attn n-tile

using bf16 = __hip_bfloat16;
typedef __attribute__((ext_vector_type(4))) float f32x4;
typedef __attribute__((ext_vector_type(8))) short short8v;

__device__ __forceinline__ float bf2f(bf16 x) { return __bfloat162float(x); }
__device__ __forceinline__ float bfs2f(short s) {
    unsigned int u = ((unsigned int)(unsigned short)s) << 16;
    return __uint_as_float(u);
}
__device__ __forceinline__ unsigned short f2bf(float x) {
    unsigned int u = __float_as_uint(x);
    unsigned int r = (u + 0x7fffu + ((u >> 16) & 1u)) >> 16;
    return (unsigned short)r;
}

// ---------------------------------------------------------------------------
// Transpose+convert: W [K][N] f32 -> Wt [N][K] bf16. 256 thr = 32x8.
// ---------------------------------------------------------------------------
__global__ __launch_bounds__(256) void transpose_w_bf16(
    const float* __restrict__ W, bf16* __restrict__ Wt, int K, int N)
{
    __shared__ float t[32][33];
    int tx = threadIdx.x & 31, ty = threadIdx.x >> 5;
    int k0 = blockIdx.y * 32, n0 = blockIdx.x * 32;
#pragma unroll
    for (int i = 0; i < 4; ++i)
        t[ty + 8 * i][tx] = W[(size_t)(k0 + ty + 8 * i) * N + n0 + tx];
    __syncthreads();
#pragma unroll
    for (int i = 0; i < 4; ++i)
        Wt[(size_t)(n0 + ty + 8 * i) * K + k0 + tx] = __float2bfloat16(t[tx][ty + 8 * i]);
}

// ---------------------------------------------------------------------------
// MFMA GEMM: C[M,N] = A[M,K] @ Bt[N,K]^T, bf16 MFMA, f32 accum.
// ---------------------------------------------------------------------------
template<bool AF32, bool OUTF32>
__global__ __launch_bounds__(256) void gemm_mfma(
    const void* __restrict__ Ap, const bf16* __restrict__ Bt,
    const float* __restrict__ bias, void* __restrict__ Cp,
    int M, int N, int K)
{
    __shared__ short As[128][40];
    __shared__ short Bs[128][40];
    int tid = threadIdx.x;
    int wave = tid >> 6, lane = tid & 63;
    int m0 = blockIdx.y * 128, n0 = blockIdx.x * 128;
    int wm = (wave >> 1) * 64, wn = (wave & 1) * 64;

    f32x4 acc[4][4] = {};

    const short* Ab = (const short*)Ap;
    const float* Af = (const float*)Ap;
    const short* Btb = (const short*)Bt;

    for (int k0 = 0; k0 < K; k0 += 32) {
        if constexpr (AF32) {
#pragma unroll
            for (int it = 0; it < 4; ++it) {
                int idx = tid + 256 * it;
                int row = idx >> 3, kp = (idx & 7) * 4;
                float4 v = *reinterpret_cast<const float4*>(
                    Af + (size_t)(m0 + row) * K + k0 + kp);
                unsigned int w0 = (unsigned int)f2bf(v.x) | ((unsigned int)f2bf(v.y) << 16);
                unsigned int w1 = (unsigned int)f2bf(v.z) | ((unsigned int)f2bf(v.w) << 16);
                uint2 pk; pk.x = w0; pk.y = w1;
                *reinterpret_cast<uint2*>(&As[row][kp]) = pk;
            }
        } else {
#pragma unroll
            for (int it = 0; it < 2; ++it) {
                int idx = tid + 256 * it;
                int row = idx >> 2, kp = (idx & 3) * 8;
                short8v v = *reinterpret_cast<const short8v*>(
                    Ab + (size_t)(m0 + row) * K + k0 + kp);
                *reinterpret_cast<short8v*>(&As[row][kp]) = v;
            }
        }
#pragma unroll
        for (int it = 0; it < 2; ++it) {
            int idx = tid + 256 * it;
            int row = idx >> 2, kp = (idx & 3) * 8;
            short8v v = *reinterpret_cast<const short8v*>(
                Btb + (size_t)(n0 + row) * K + k0 + kp);
            *reinterpret_cast<short8v*>(&Bs[row][kp]) = v;
        }
        __syncthreads();

        short8v af[4], bfr[4];
#pragma unroll
        for (int mf = 0; mf < 4; ++mf)
            af[mf] = *reinterpret_cast<const short8v*>(
                &As[wm + mf * 16 + (lane & 15)][(lane >> 4) * 8]);
#pragma unroll
        for (int nf = 0; nf < 4; ++nf)
            bfr[nf] = *reinterpret_cast<const short8v*>(
                &Bs[wn + nf * 16 + (lane & 15)][(lane >> 4) * 8]);
#pragma unroll
        for (int mf = 0; mf < 4; ++mf)
#pragma unroll
            for (int nf = 0; nf < 4; ++nf)
                acc[mf][nf] = __builtin_amdgcn_mfma_f32_16x16x32_bf16(
                    af[mf], bfr[nf], acc[mf][nf], 0, 0, 0);
        __syncthreads();
    }

    int rgrp = (lane >> 4) * 4, cidx = lane & 15;
#pragma unroll
    for (int mf = 0; mf < 4; ++mf)
#pragma unroll
        for (int nf = 0; nf < 4; ++nf)
#pragma unroll
            for (int r = 0; r < 4; ++r) {
                int row = m0 + wm + mf * 16 + rgrp + r;
                int col = n0 + wn + nf * 16 + cidx;
                float v = acc[mf][nf][r];
                if constexpr (OUTF32)
                    ((float*)Cp)[(size_t)row * N + col] = v + bias[col];
                else
                    ((bf16*)Cp)[(size_t)row * N + col] = __float2bfloat16(v);
            }
}

// ---------------------------------------------------------------------------
// Pool: ahp[b][a][c] = mean over 4x4 block of q[b][n][c]  (bf16 in, f32 out)
// ---------------------------------------------------------------------------
__global__ void pool_kernel(const bf16* __restrict__ q, float* __restrict__ ahp)
{
    int idx = blockIdx.x * 256 + threadIdx.x;
    if (idx >= BATCH * AGENT * DIM) return;
    int c = idx % DIM;
    int a = (idx / DIM) % AGENT;
    int b = idx / (DIM * AGENT);
    int ai = a / 7, aj = a % 7;
    float s = 0.f;
#pragma unroll
    for (int u = 0; u < 4; ++u)
#pragma unroll
        for (int v = 0; v < 4; ++v) {
            int n = (ai * 4 + u) * WW + (aj * 4 + v);
            s += bf2f(q[((size_t)b * NPOS + n) * DIM + c]);
        }
    ahp[idx] = s * (1.f / 16.f);
}

// ---------------------------------------------------------------------------
// Bilinear 7->28 upsample, half-pixel centers, edge clamp
// ---------------------------------------------------------------------------
__device__ __forceinline__ float bilerp7(const float* __restrict__ img, int i, int j)
{
    float si = 0.25f * i - 0.375f, sj = 0.25f * j - 0.375f;
    int i0 = (int)floorf(si); float fi = si - i0;
    int j0 = (int)floorf(sj); float fj = sj - j0;
    int i0c = min(max(i0, 0), 6), i1c = min(max(i0 + 1, 0), 6);
    int j0c = min(max(j0, 0), 6), j1c = min(max(j0 + 1, 0), 6);
    float v00 = img[i0c * 7 + j0c], v01 = img[i0c * 7 + j1c];
    float v10 = img[i1c * 7 + j0c], v11 = img[i1c * 7 + j1c];
    return (1.f - fi) * ((1.f - fj) * v00 + fj * v01) + fi * ((1.f - fj) * v10 + fj * v11);
}

__global__ void pos_bias_kernel(const float* __restrict__ an, const float* __restrict__ ah_b,
                                const float* __restrict__ aw_b, bf16* __restrict__ pb)
{
    int idx = blockIdx.x * 256 + threadIdx.x;
    if (idx >= HEADS * AGENT * NPOS) return;
    int n = idx % NPOS;
    int a = (idx / NPOS) % AGENT;
    int h = idx / (NPOS * AGENT);
    int i = n / WW, j = n % WW;
    float v = bilerp7(an + (size_t)(h * AGENT + a) * 49, i, j);
    v += ah_b[(h * AGENT + a) * HH + i] + aw_b[(h * AGENT + a) * WW + j];
    pb[idx] = __float2bfloat16(v);
}

__global__ void ag_bias_kernel(const float* __restrict__ na, const float* __restrict__ ha_b,
                               const float* __restrict__ wa_b, bf16* __restrict__ ab)
{
    int idx = blockIdx.x * 256 + threadIdx.x;
    if (idx >= HEADS * NPOS * AGENT) return;
    int a = idx % AGENT;
    int n = (idx / AGENT) % NPOS;
    int h = idx / (AGENT * NPOS);
    int i = n / WW, j = n % WW;
    float v = bilerp7(na + (size_t)(h * AGENT + a) * 49, i, j);
    v += ha_b[(h * HH + i) * AGENT + a] + wa_b[(h * WW + j) * AGENT + a];
    ab[idx] = __float2bfloat16(v);
}

// ---------------------------------------------------------------------------
// Agent attention v2: one block per (b,h). Flash-style online softmax over
// 7 tiles of NT=112 key rows. K/V tiles + Q staged in LDS (16B-chunk XOR
// swizzle vs stride-128B bank conflicts); O accumulator in registers
// (thread owns (a,dseg) slots). LDS ~58.5 KB -> 2 blocks/CU.
// ---------------------------------------------------------------------------
__global__ __launch_bounds__(256) void agent_attn2(
    const float* __restrict__ ahp, const bf16* __restrict__ kv,
    const bf16* __restrict__ pb, bf16* __restrict__ agent_v)
{
    __shared__ short qsS[AGENT][64];   // bf16 q*scale, chunk-swizzled by (a&7)
    __shared__ short Kt[NT][64];       // chunk-swizzled by (n&7)
    __shared__ short Vt[NT][64];       // chunk-swizzled by (n&7)
    __shared__ float S[AGENT][117];    // scores / P (pad 117: conflict-free)
    __shared__ float mrow[AGENT], lrow[AGENT], frow[AGENT];

    int tid = threadIdx.x;
    int h = blockIdx.x % HEADS;
    int b = blockIdx.x / HEADS;

    // stage Q (49x64 f32 -> bf16, *SCALE), swizzled
    for (int i = tid; i < AGENT * 8; i += 256) {
        int a = i >> 3, seg = i & 7;
        const float* src = ahp + ((size_t)b * AGENT + a) * DIM + h * HD + seg * 8;
        float4 r0 = *reinterpret_cast<const float4*>(src);
        float4 r1 = *reinterpret_cast<const float4*>(src + 4);
        short8v v;
        v[0] = (short)f2bf(r0.x * SCALE); v[1] = (short)f2bf(r0.y * SCALE);
        v[2] = (short)f2bf(r0.z * SCALE); v[3] = (short)f2bf(r0.w * SCALE);
        v[4] = (short)f2bf(r1.x * SCALE); v[5] = (short)f2bf(r1.y * SCALE);
        v[6] = (short)f2bf(r1.z * SCALE); v[7] = (short)f2bf(r1.w * SCALE);
        *reinterpret_cast<short8v*>(&qsS[a][(seg ^ (a & 7)) * 8]) = v;
    }
    if (tid < AGENT) { mrow[tid] = -1e30f; lrow[tid] = 0.f; }

    // per-thread O slots: slot s -> a = s>>3, dseg = s&7 (49*8 = 392 slots)
    float o0[8] = {}, o1[8] = {};
    int s0 = tid, s1 = 256 + tid;
    bool has1 = (s1 < AGENT * 8);

    for (int t = 0; t < 7; ++t) {
        int n0 = t * NT;
        __syncthreads();   // protect Kt/Vt/S from previous iteration readers
        // stage K,V tile (swizzled)
        for (int i = tid; i < NT * 8; i += 256) {
            int n = i >> 3, seg = i & 7;
            const short* base = (const short*)kv +
                ((size_t)(b * NPOS + n0 + n)) * (2 * DIM) + h * HD + seg * 8;
            int sw = (seg ^ (n & 7)) * 8;
            *reinterpret_cast<short8v*>(&Kt[n][sw]) =
                *reinterpret_cast<const short8v*>(base);
            *reinterpret_cast<short8v*>(&Vt[n][sw]) =
                *reinterpret_cast<const short8v*>(base + DIM);
        }
        __syncthreads();

        // S[a][n] = q_a . k_n + pb   (a fastest -> K row ~broadcast)
        for (int i = tid; i < AGENT * NT; i += 256) {
            int a = i % AGENT, n = i / AGENT;
            float acc = 0.f;
#pragma unroll
            for (int d8 = 0; d8 < 8; ++d8) {
                short8v qv = *reinterpret_cast<const short8v*>(&qsS[a][(d8 ^ (a & 7)) * 8]);
                short8v kvv = *reinterpret_cast<const short8v*>(&Kt[n][(d8 ^ (n & 7)) * 8]);
#pragma unroll
                for (int u = 0; u < 8; ++u)
                    acc += bfs2f(qv[u]) * bfs2f(kvv[u]);
            }
            acc += bf2f(pb[((size_t)h * AGENT + a) * NPOS + n0 + n]);
            S[a][n] = acc;
        }
        __syncthreads();

        // online softmax row update (threads 0..48)
        if (tid < AGENT) {
            float m_old = mrow[tid];
            float m_new = m_old;
            for (int n = 0; n < NT; ++n) m_new = fmaxf(m_new, S[tid][n]);
            float fac = __expf(m_old - m_new);
            float ls = 0.f;
            for (int n = 0; n < NT; ++n) {
                float p = __expf(S[tid][n] - m_new);
                S[tid][n] = p;
                ls += p;
            }
            mrow[tid] = m_new;
            lrow[tid] = lrow[tid] * fac + ls;
            frow[tid] = fac;
        }
        __syncthreads();

        // O = O*fac + P @ V
        {
            int a = s0 >> 3, dseg = s0 & 7;
            float fac = frow[a];
#pragma unroll
            for (int u = 0; u < 8; ++u) o0[u] *= fac;
            for (int n = 0; n < NT; ++n) {
                float p = S[a][n];
                short8v vv = *reinterpret_cast<const short8v*>(&Vt[n][(dseg ^ (n & 7)) * 8]);
#pragma unroll
                for (int u = 0; u < 8; ++u) o0[u] += p * bfs2f(vv[u]);
            }
        }
        if (has1) {
            int a = s1 >> 3, dseg = s1 & 7;
            float fac = frow[a];
#pragma unroll
            for (int u = 0; u < 8; ++u) o1[u] *= fac;
            for (int n = 0; n < NT; ++n) {
                float p = S[a][n];
                short8v vv = *reinterpret_cast<const short8v*>(&Vt[n][(dseg ^ (n & 7)) * 8]);
#pragma unroll
                for (int u = 0; u < 8; ++u) o1[u] += p * bfs2f(vv[u]);
            }
        }
    }
    __syncthreads();

    // write out: agent_v[b][h][a][d]
    {
        int a = s0 >> 3, dseg = s0 & 7;
        float inv = 1.f / lrow[a];
        short8v v;
#pragma unroll
        for (int u = 0; u < 8; ++u) v[u] = (short)f2bf(o0[u] * inv);
        *reinterpret_cast<short8v*>((short*)agent_v +
            (((size_t)b * HEADS + h) * AGENT + a) * HD + dseg * 8) = v;
    }
    if (has1) {
        int a = s1 >> 3, dseg = s1 & 7;
        float inv = 1.f / lrow[a];
        short8v v;
#pragma unroll
        for (int u = 0; u < 8; ++u) v[u] = (short)f2bf(o1[u] * inv);
        *reinterpret_cast<short8v*>((short*)agent_v +
            (((size_t)b * HEADS + h) * AGENT + a) * HD + dseg * 8) = v;
    }
}

// ---------------------------------------------------------------------------
// Q attention + fused depthwise conv, IN-PLACE over q. Shuffle-free.
// ---------------------------------------------------------------------------
__global__ __launch_bounds__(256) void q_attn_dwc2(
    bf16* qpre, const bf16* __restrict__ kv_own,
    const float* __restrict__ ahp_x, const bf16* __restrict__ ab_x,
    const bf16* __restrict__ agv_x,
    const float* __restrict__ dwc_w, const float* __restrict__ dwc_b)
{
    __shared__ float ahT[64][65];   // [d][a], padded; a>=49 zero
    __shared__ float avS[AGENT][64];
    __shared__ float pS[16][64];
    int tid = threadIdx.x;
    int blk = blockIdx.x;
    int chunk = blk % 49;
    int h = (blk / 49) % HEADS;
    int b = blk / (49 * HEADS);

    for (int i = tid; i < 64 * 64; i += 256) {
        int a = i >> 6, d = i & 63;
        ahT[d][a] = (a < AGENT) ? ahp_x[((size_t)b * AGENT + a) * DIM + h * HD + d] : 0.f;
    }
    for (int i = tid; i < AGENT * 64; i += 256) {
        int a = i >> 6, d = i & 63;
        avS[a][d] = bf2f(agv_x[(((size_t)b * HEADS + h) * AGENT + a) * HD + d]);
    }
    __syncthreads();

    int wave = tid >> 6, lane = tid & 63;
    int c = h * HD + lane;
    float wv[9];
#pragma unroll
    for (int t = 0; t < 9; ++t) wv[t] = dwc_w[t * DIM + c];
    float cb = dwc_b[c];

#pragma unroll
    for (int r = 0; r < 4; ++r) {
        int rl = wave * 4 + r;
        int n = chunk * 16 + rl;
        const unsigned int* q32 =
            (const unsigned int*)(qpre + (size_t)(b * NPOS + n) * DIM + h * HD);
        float acc = 0.f;
#pragma unroll
        for (int dp = 0; dp < 32; ++dp) {
            unsigned int u = q32[dp];
            float qlo = __uint_as_float(u << 16);
            float qhi = __uint_as_float(u & 0xffff0000u);
            acc += qlo * ahT[2 * dp][lane] + qhi * ahT[2 * dp + 1][lane];
        }
        float sa = (lane < AGENT)
                       ? (acc * SCALE + bf2f(ab_x[((size_t)h * NPOS + n) * AGENT + lane]))
                       : -1e30f;
        float mx = sa;
#pragma unroll
        for (int off = 32; off > 0; off >>= 1) mx = fmaxf(mx, __shfl_xor(mx, off));
        float p = (lane < AGENT) ? __expf(sa - mx) : 0.f;
        float sm = p;
#pragma unroll
        for (int off = 32; off > 0; off >>= 1) sm += __shfl_xor(sm, off);
        pS[rl][lane] = p / sm;
    }

#pragma unroll
    for (int r = 0; r < 4; ++r) {
        int rl = wave * 4 + r;
        int n = chunk * 16 + rl;
        int i = n / WW, j = n % WW;
        float o = 0.f;
#pragma unroll
        for (int a = 0; a < AGENT; ++a)
            o += pS[rl][a] * avS[a][lane];

        float conv = cb;
#pragma unroll
        for (int di = -1; di <= 1; ++di) {
            int ii = i + di;
            if (ii < 0 || ii >= HH) continue;
#pragma unroll
            for (int dj = -1; dj <= 1; ++dj) {
                int jj = j + dj;
                if (jj < 0 || jj >= WW) continue;
                conv += wv[(di + 1) * 3 + (dj + 1)] *
                        bf2f(kv_own[((size_t)(b * NPOS + ii * WW + jj)) * (2 * DIM) + DIM + c]);
            }
        }
        qpre[(size_t)(b * NPOS + n) * DIM + c] = __float2bfloat16(o + conv);
    }
}

// ---------------------------------------------------------------------------
extern "C" void kernel_launch(void* const* d_in, const int* in_sizes, int n_in,
                              void* d_out, int out_size, void* d_ws, size_t ws_size,
                              hipStream_t stream)
{
    const float* rgb_fea    = (const float*)d_in[0];
    const float* depth_fea  = (const float*)d_in[1];
    const float* rgb_q_w    = (const float*)d_in[2];
    const float* rgb_kv_w   = (const float*)d_in[3];
    const float* rgb_proj_w = (const float*)d_in[4];
    const float* rgb_proj_b = (const float*)d_in[5];
    const float* depth_q_w    = (const float*)d_in[6];
    const float* depth_kv_w   = (const float*)d_in[7];
    const float* depth_proj_w = (const float*)d_in[8];
    const float* depth_proj_b = (const float*)d_in[9];
    const float* rgb_dwc_w   = (const float*)d_in[10];
    const float* rgb_dwc_b   = (const float*)d_in[11];
    const float* depth_dwc_w = (const float*)d_in[12];
    const float* depth_dwc_b = (const float*)d_in[13];
    const float* rgb_an   = (const float*)d_in[14];
    const float* rgb_na   = (const float*)d_in[15];
    const float* rgb_ah_b = (const float*)d_in[16];
    const float* rgb_aw_b = (const float*)d_in[17];
    const float* rgb_ha_b = (const float*)d_in[18];
    const float* rgb_wa_b = (const float*)d_in[19];
    const float* depth_an   = (const float*)d_in[20];
    const float* depth_na   = (const float*)d_in[21];
    const float* depth_ah_b = (const float*)d_in[22];
    const float* depth_aw_b = (const float*)d_in[23];
    const float* depth_ha_b = (const float*)d_in[24];
    const float* depth_wa_b = (const float*)d_in[25];

    char* ws = (char*)d_ws;
    size_t off = 0;
    auto alloc = [&](size_t bytes) -> void* {
        void* p = ws + off;
        off += (bytes + 255) & ~(size_t)255;
        return p;
    };
    // persistent (~242 MB)
    bf16* rgb_q    = (bf16*)alloc((size_t)MROWS * DIM * 2);
    bf16* depth_q  = (bf16*)alloc((size_t)MROWS * DIM * 2);
    bf16* rgb_kv   = (bf16*)alloc((size_t)MROWS * 2 * DIM * 2);
    bf16* depth_kv = (bf16*)alloc((size_t)MROWS * 2 * DIM * 2);
    bf16* rgb_pb    = (bf16*)alloc((size_t)HEADS * AGENT * NPOS * 2);
    bf16* depth_pb  = (bf16*)alloc((size_t)HEADS * AGENT * NPOS * 2);
    bf16* rgb_ab    = (bf16*)alloc((size_t)HEADS * NPOS * AGENT * 2);
    bf16* depth_ab  = (bf16*)alloc((size_t)HEADS * NPOS * AGENT * 2);
    bf16* rgb_agv   = (bf16*)alloc((size_t)BATCH * HEADS * AGENT * HD * 2);
    bf16* depth_agv = (bf16*)alloc((size_t)BATCH * HEADS * AGENT * HD * 2);
    bf16* proj_wt_r = (bf16*)alloc((size_t)DIM * DIM * 2);
    bf16* proj_wt_d = (bf16*)alloc((size_t)DIM * DIM * 2);
    // union region (~9.7 MB): {q_wt, kv_wt} dead before {ahp} written
    size_t ubase = off;
    bf16* q_wt_r  = (bf16*)alloc((size_t)DIM * DIM * 2);
    bf16* kv_wt_r = (bf16*)alloc((size_t)DIM * 2 * DIM * 2);
    bf16* q_wt_d  = (bf16*)alloc((size_t)DIM * DIM * 2);
    bf16* kv_wt_d = (bf16*)alloc((size_t)DIM * 2 * DIM * 2);
    off = ubase;  // alias
    float* rgb_ahp   = (float*)alloc((size_t)BATCH * AGENT * DIM * 4);
    float* depth_ahp = (float*)alloc((size_t)BATCH * AGENT * DIM * 4);

    dim3 blk(256);

    // 0) weight transposes (f32 [K][N] -> bf16 [N][K])
    transpose_w_bf16<<<dim3(24, 24), blk, 0, stream>>>(rgb_q_w, q_wt_r, DIM, DIM);
    transpose_w_bf16<<<dim3(48, 24), blk, 0, stream>>>(rgb_kv_w, kv_wt_r, DIM, 2 * DIM);
    transpose_w_bf16<<<dim3(24, 24), blk, 0, stream>>>(depth_q_w, q_wt_d, DIM, DIM);
    transpose_w_bf16<<<dim3(48, 24), blk, 0, stream>>>(depth_kv_w, kv_wt_d, DIM, 2 * DIM);
    transpose_w_bf16<<<dim3(24, 24), blk, 0, stream>>>(rgb_proj_w, proj_wt_r, DIM, DIM);
    transpose_w_bf16<<<dim3(24, 24), blk, 0, stream>>>(depth_proj_w, proj_wt_d, DIM, DIM);

    // 1) q / kv projections (MFMA; f32 A converted in staging)
    gemm_mfma<true, false><<<dim3(6, 196), blk, 0, stream>>>(rgb_fea, q_wt_r, nullptr, rgb_q, MROWS, DIM, DIM);
    gemm_mfma<true, false><<<dim3(6, 196), blk, 0, stream>>>(depth_fea, q_wt_d, nullptr, depth_q, MROWS, DIM, DIM);
    gemm_mfma<true, false><<<dim3(12, 196), blk, 0, stream>>>(rgb_fea, kv_wt_r, nullptr, rgb_kv, MROWS, 2 * DIM, DIM);
    gemm_mfma<true, false><<<dim3(12, 196), blk, 0, stream>>>(depth_fea, kv_wt_d, nullptr, depth_kv, MROWS, 2 * DIM, DIM);

    // 2) agent pooling of q (writes ahp over dead q_wt/kv_wt region)
    pool_kernel<<<(BATCH * AGENT * DIM + 255) / 256, blk, 0, stream>>>(rgb_q, rgb_ahp);
    pool_kernel<<<(BATCH * AGENT * DIM + 255) / 256, blk, 0, stream>>>(depth_q, depth_ahp);

    // 3) position biases
    pos_bias_kernel<<<(HEADS * AGENT * NPOS + 255) / 256, blk, 0, stream>>>(rgb_an, rgb_ah_b, rgb_aw_b, rgb_pb);
    pos_bias_kernel<<<(HEADS * AGENT * NPOS + 255) / 256, blk, 0, stream>>>(depth_an, depth_ah_b, depth_aw_b, depth_pb);
    ag_bias_kernel<<<(HEADS * NPOS * AGENT + 255) / 256, blk, 0, stream>>>(rgb_na, rgb_ha_b, rgb_wa_b, rgb_ab);
    ag_bias_kernel<<<(HEADS * NPOS * AGENT + 255) / 256, blk, 0, stream>>>(depth_na, depth_ha_b, depth_wa_b, depth_ab);

    // 4) cross-modal agent aggregation (one block per (b,h))
    agent_attn2<<<BATCH * HEADS, blk, 0, stream>>>(depth_ahp, rgb_kv, rgb_pb, depth_agv);
    agent_attn2<<<BATCH * HEADS, blk, 0, stream>>>(rgb_ahp, depth_kv, depth_pb, rgb_agv);

    // 5) agent broadcast + fused depthwise conv (in-place q -> pre)
    q_attn_dwc2<<<BATCH * HEADS * 49, blk, 0, stream>>>(rgb_q, rgb_kv, depth_ahp, depth_ab, depth_agv,
                                                        rgb_dwc_w, rgb_dwc_b);
    q_attn_dwc2<<<BATCH * HEADS * 49, blk, 0, stream>>>(depth_q, depth_kv, rgb_ahp, rgb_ab, rgb_agv,
                                                        depth_dwc_w, depth_dwc_b);

    // 6) output projections (MFMA, bf16 A, f32 out + bias)
    float* out = (float*)d_out;
    gemm_mfma<false, true><<<dim3(6, 196), blk, 0, stream>>>(rgb_q, proj_wt_r, rgb_proj_b, out, MROWS, DIM, DIM);
    gemm_mfma<false, true><<<dim3(6, 196), blk, 0, stream>>>(depth_q, proj_wt_d, depth_proj_b,
                                                             out + (size_t)MROWS * DIM, MROWS, DIM, DIM);
}

// Round 6
// 1487.516 us; speedup vs baseline: 4.5712x; 1.5644x over previous
//
#include <hip/hip_runtime.h>
#include <hip/hip_bf16.h>

#define BATCH 32
#define NPOS 784
#define DIM 768
#define HEADS 12
#define HD 64
#define AGENT 49
#define HH 28
#define WW 28
#define MROWS (BATCH*NPOS)   // 25088
#define SCALE 0.125f
#define NT 112               // 784 = 7*112, agent-attn n-tile

using bf16 = __hip_bfloat16;
typedef __attribute__((ext_vector_type(4))) float f32x4;
typedef __attribute__((ext_vector_type(8))) short short8v;

__device__ __forceinline__ float bf2f(bf16 x) { return __bfloat162float(x); }
__device__ __forceinline__ float bfs2f(short s) {
    unsigned int u = ((unsigned int)(unsigned short)s) << 16;
    return __uint_as_float(u);
}
__device__ __forceinline__ unsigned short f2bf(float x) {
    unsigned int u = __float_as_uint(x);
    unsigned int r = (u + 0x7fffu + ((u >> 16) & 1u)) >> 16;
    return (unsigned short)r;
}

// ---------------------------------------------------------------------------
// Transpose+convert: W [K][N] f32 -> Wt [N][K] bf16. 256 thr = 32x8.
// ---------------------------------------------------------------------------
__global__ __launch_bounds__(256) void transpose_w_bf16(
    const float* __restrict__ W, bf16* __restrict__ Wt, int K, int N)
{
    __shared__ float t[32][33];
    int tx = threadIdx.x & 31, ty = threadIdx.x >> 5;
    int k0 = blockIdx.y * 32, n0 = blockIdx.x * 32;
#pragma unroll
    for (int i = 0; i < 4; ++i)
        t[ty + 8 * i][tx] = W[(size_t)(k0 + ty + 8 * i) * N + n0 + tx];
    __syncthreads();
#pragma unroll
    for (int i = 0; i < 4; ++i)
        Wt[(size_t)(n0 + ty + 8 * i) * K + k0 + tx] = __float2bfloat16(t[tx][ty + 8 * i]);
}

// ---------------------------------------------------------------------------
// MFMA GEMM: C[M,N] = A[M,K] @ Bt[N,K]^T, bf16 MFMA, f32 accum.
// ---------------------------------------------------------------------------
template<bool AF32, bool OUTF32>
__global__ __launch_bounds__(256) void gemm_mfma(
    const void* __restrict__ Ap, const bf16* __restrict__ Bt,
    const float* __restrict__ bias, void* __restrict__ Cp,
    int M, int N, int K)
{
    __shared__ short As[128][40];
    __shared__ short Bs[128][40];
    int tid = threadIdx.x;
    int wave = tid >> 6, lane = tid & 63;
    int m0 = blockIdx.y * 128, n0 = blockIdx.x * 128;
    int wm = (wave >> 1) * 64, wn = (wave & 1) * 64;

    f32x4 acc[4][4] = {};

    const short* Ab = (const short*)Ap;
    const float* Af = (const float*)Ap;
    const short* Btb = (const short*)Bt;

    for (int k0 = 0; k0 < K; k0 += 32) {
        if constexpr (AF32) {
#pragma unroll
            for (int it = 0; it < 4; ++it) {
                int idx = tid + 256 * it;
                int row = idx >> 3, kp = (idx & 7) * 4;
                float4 v = *reinterpret_cast<const float4*>(
                    Af + (size_t)(m0 + row) * K + k0 + kp);
                unsigned int w0 = (unsigned int)f2bf(v.x) | ((unsigned int)f2bf(v.y) << 16);
                unsigned int w1 = (unsigned int)f2bf(v.z) | ((unsigned int)f2bf(v.w) << 16);
                uint2 pk; pk.x = w0; pk.y = w1;
                *reinterpret_cast<uint2*>(&As[row][kp]) = pk;
            }
        } else {
#pragma unroll
            for (int it = 0; it < 2; ++it) {
                int idx = tid + 256 * it;
                int row = idx >> 2, kp = (idx & 3) * 8;
                short8v v = *reinterpret_cast<const short8v*>(
                    Ab + (size_t)(m0 + row) * K + k0 + kp);
                *reinterpret_cast<short8v*>(&As[row][kp]) = v;
            }
        }
#pragma unroll
        for (int it = 0; it < 2; ++it) {
            int idx = tid + 256 * it;
            int row = idx >> 2, kp = (idx & 3) * 8;
            short8v v = *reinterpret_cast<const short8v*>(
                Btb + (size_t)(n0 + row) * K + k0 + kp);
            *reinterpret_cast<short8v*>(&Bs[row][kp]) = v;
        }
        __syncthreads();

        short8v af[4], bfr[4];
#pragma unroll
        for (int mf = 0; mf < 4; ++mf)
            af[mf] = *reinterpret_cast<const short8v*>(
                &As[wm + mf * 16 + (lane & 15)][(lane >> 4) * 8]);
#pragma unroll
        for (int nf = 0; nf < 4; ++nf)
            bfr[nf] = *reinterpret_cast<const short8v*>(
                &Bs[wn + nf * 16 + (lane & 15)][(lane >> 4) * 8]);
#pragma unroll
        for (int mf = 0; mf < 4; ++mf)
#pragma unroll
            for (int nf = 0; nf < 4; ++nf)
                acc[mf][nf] = __builtin_amdgcn_mfma_f32_16x16x32_bf16(
                    af[mf], bfr[nf], acc[mf][nf], 0, 0, 0);
        __syncthreads();
    }

    int rgrp = (lane >> 4) * 4, cidx = lane & 15;
#pragma unroll
    for (int mf = 0; mf < 4; ++mf)
#pragma unroll
        for (int nf = 0; nf < 4; ++nf)
#pragma unroll
            for (int r = 0; r < 4; ++r) {
                int row = m0 + wm + mf * 16 + rgrp + r;
                int col = n0 + wn + nf * 16 + cidx;
                float v = acc[mf][nf][r];
                if constexpr (OUTF32)
                    ((float*)Cp)[(size_t)row * N + col] = v + bias[col];
                else
                    ((bf16*)Cp)[(size_t)row * N + col] = __float2bfloat16(v);
            }
}

// ---------------------------------------------------------------------------
// Pool: ahp[b][a][c] = mean over 4x4 block of q[b][n][c]  (bf16 in, f32 out)
// ---------------------------------------------------------------------------
__global__ void pool_kernel(const bf16* __restrict__ q, float* __restrict__ ahp)
{
    int idx = blockIdx.x * 256 + threadIdx.x;
    if (idx >= BATCH * AGENT * DIM) return;
    int c = idx % DIM;
    int a = (idx / DIM) % AGENT;
    int b = idx / (DIM * AGENT);
    int ai = a / 7, aj = a % 7;
    float s = 0.f;
#pragma unroll
    for (int u = 0; u < 4; ++u)
#pragma unroll
        for (int v = 0; v < 4; ++v) {
            int n = (ai * 4 + u) * WW + (aj * 4 + v);
            s += bf2f(q[((size_t)b * NPOS + n) * DIM + c]);
        }
    ahp[idx] = s * (1.f / 16.f);
}

// ---------------------------------------------------------------------------
// Bilinear 7->28 upsample, half-pixel centers, edge clamp
// ---------------------------------------------------------------------------
__device__ __forceinline__ float bilerp7(const float* __restrict__ img, int i, int j)
{
    float si = 0.25f * i - 0.375f, sj = 0.25f * j - 0.375f;
    int i0 = (int)floorf(si); float fi = si - i0;
    int j0 = (int)floorf(sj); float fj = sj - j0;
    int i0c = min(max(i0, 0), 6), i1c = min(max(i0 + 1, 0), 6);
    int j0c = min(max(j0, 0), 6), j1c = min(max(j0 + 1, 0), 6);
    float v00 = img[i0c * 7 + j0c], v01 = img[i0c * 7 + j1c];
    float v10 = img[i1c * 7 + j0c], v11 = img[i1c * 7 + j1c];
    return (1.f - fi) * ((1.f - fj) * v00 + fj * v01) + fi * ((1.f - fj) * v10 + fj * v11);
}

__global__ void pos_bias_kernel(const float* __restrict__ an, const float* __restrict__ ah_b,
                                const float* __restrict__ aw_b, bf16* __restrict__ pb)
{
    int idx = blockIdx.x * 256 + threadIdx.x;
    if (idx >= HEADS * AGENT * NPOS) return;
    int n = idx % NPOS;
    int a = (idx / NPOS) % AGENT;
    int h = idx / (NPOS * AGENT);
    int i = n / WW, j = n % WW;
    float v = bilerp7(an + (size_t)(h * AGENT + a) * 49, i, j);
    v += ah_b[(h * AGENT + a) * HH + i] + aw_b[(h * AGENT + a) * WW + j];
    pb[idx] = __float2bfloat16(v);
}

__global__ void ag_bias_kernel(const float* __restrict__ na, const float* __restrict__ ha_b,
                               const float* __restrict__ wa_b, bf16* __restrict__ ab)
{
    int idx = blockIdx.x * 256 + threadIdx.x;
    if (idx >= HEADS * NPOS * AGENT) return;
    int a = idx % AGENT;
    int n = (idx / AGENT) % NPOS;
    int h = idx / (AGENT * NPOS);
    int i = n / WW, j = n % WW;
    float v = bilerp7(na + (size_t)(h * AGENT + a) * 49, i, j);
    v += ha_b[(h * HH + i) * AGENT + a] + wa_b[(h * WW + j) * AGENT + a];
    ab[idx] = __float2bfloat16(v);
}

// ---------------------------------------------------------------------------
// Agent attention v2: one block per (b,h), flash-style over 7 tiles of 112.
// ---------------------------------------------------------------------------
__global__ __launch_bounds__(256) void agent_attn2(
    const float* __restrict__ ahp, const bf16* __restrict__ kv,
    const bf16* __restrict__ pb, bf16* __restrict__ agent_v)
{
    __shared__ short qsS[AGENT][64];
    __shared__ short Kt[NT][64];
    __shared__ short Vt[NT][64];
    __shared__ float S[AGENT][117];
    __shared__ float mrow[AGENT], lrow[AGENT], frow[AGENT];

    int tid = threadIdx.x;
    int h = blockIdx.x % HEADS;
    int b = blockIdx.x / HEADS;

    for (int i = tid; i < AGENT * 8; i += 256) {
        int a = i >> 3, seg = i & 7;
        const float* src = ahp + ((size_t)b * AGENT + a) * DIM + h * HD + seg * 8;
        float4 r0 = *reinterpret_cast<const float4*>(src);
        float4 r1 = *reinterpret_cast<const float4*>(src + 4);
        short8v v;
        v[0] = (short)f2bf(r0.x * SCALE); v[1] = (short)f2bf(r0.y * SCALE);
        v[2] = (short)f2bf(r0.z * SCALE); v[3] = (short)f2bf(r0.w * SCALE);
        v[4] = (short)f2bf(r1.x * SCALE); v[5] = (short)f2bf(r1.y * SCALE);
        v[6] = (short)f2bf(r1.z * SCALE); v[7] = (short)f2bf(r1.w * SCALE);
        *reinterpret_cast<short8v*>(&qsS[a][(seg ^ (a & 7)) * 8]) = v;
    }
    if (tid < AGENT) { mrow[tid] = -1e30f; lrow[tid] = 0.f; }

    float o0[8] = {}, o1[8] = {};
    int s0 = tid, s1 = 256 + tid;
    bool has1 = (s1 < AGENT * 8);

    for (int t = 0; t < 7; ++t) {
        int n0 = t * NT;
        __syncthreads();
        for (int i = tid; i < NT * 8; i += 256) {
            int n = i >> 3, seg = i & 7;
            const short* base = (const short*)kv +
                ((size_t)(b * NPOS + n0 + n)) * (2 * DIM) + h * HD + seg * 8;
            int sw = (seg ^ (n & 7)) * 8;
            *reinterpret_cast<short8v*>(&Kt[n][sw]) =
                *reinterpret_cast<const short8v*>(base);
            *reinterpret_cast<short8v*>(&Vt[n][sw]) =
                *reinterpret_cast<const short8v*>(base + DIM);
        }
        __syncthreads();

        for (int i = tid; i < AGENT * NT; i += 256) {
            int a = i % AGENT, n = i / AGENT;
            float acc = 0.f;
#pragma unroll
            for (int d8 = 0; d8 < 8; ++d8) {
                short8v qv = *reinterpret_cast<const short8v*>(&qsS[a][(d8 ^ (a & 7)) * 8]);
                short8v kvv = *reinterpret_cast<const short8v*>(&Kt[n][(d8 ^ (n & 7)) * 8]);
#pragma unroll
                for (int u = 0; u < 8; ++u)
                    acc += bfs2f(qv[u]) * bfs2f(kvv[u]);
            }
            acc += bf2f(pb[((size_t)h * AGENT + a) * NPOS + n0 + n]);
            S[a][n] = acc;
        }
        __syncthreads();

        if (tid < AGENT) {
            float m_old = mrow[tid];
            float m_new = m_old;
            for (int n = 0; n < NT; ++n) m_new = fmaxf(m_new, S[tid][n]);
            float fac = __expf(m_old - m_new);
            float ls = 0.f;
            for (int n = 0; n < NT; ++n) {
                float p = __expf(S[tid][n] - m_new);
                S[tid][n] = p;
                ls += p;
            }
            mrow[tid] = m_new;
            lrow[tid] = lrow[tid] * fac + ls;
            frow[tid] = fac;
        }
        __syncthreads();

        {
            int a = s0 >> 3, dseg = s0 & 7;
            float fac = frow[a];
#pragma unroll
            for (int u = 0; u < 8; ++u) o0[u] *= fac;
            for (int n = 0; n < NT; ++n) {
                float p = S[a][n];
                short8v vv = *reinterpret_cast<const short8v*>(&Vt[n][(dseg ^ (n & 7)) * 8]);
#pragma unroll
                for (int u = 0; u < 8; ++u) o0[u] += p * bfs2f(vv[u]);
            }
        }
        if (has1) {
            int a = s1 >> 3, dseg = s1 & 7;
            float fac = frow[a];
#pragma unroll
            for (int u = 0; u < 8; ++u) o1[u] *= fac;
            for (int n = 0; n < NT; ++n) {
                float p = S[a][n];
                short8v vv = *reinterpret_cast<const short8v*>(&Vt[n][(dseg ^ (n & 7)) * 8]);
#pragma unroll
                for (int u = 0; u < 8; ++u) o1[u] += p * bfs2f(vv[u]);
            }
        }
    }
    __syncthreads();

    {
        int a = s0 >> 3, dseg = s0 & 7;
        float inv = 1.f / lrow[a];
        short8v v;
#pragma unroll
        for (int u = 0; u < 8; ++u) v[u] = (short)f2bf(o0[u] * inv);
        *reinterpret_cast<short8v*>((short*)agent_v +
            (((size_t)b * HEADS + h) * AGENT + a) * HD + dseg * 8) = v;
    }
    if (has1) {
        int a = s1 >> 3, dseg = s1 & 7;
        float inv = 1.f / lrow[a];
        short8v v;
#pragma unroll
        for (int u = 0; u < 8; ++u) v[u] = (short)f2bf(o1[u] * inv);
        *reinterpret_cast<short8v*>((short*)agent_v +
            (((size_t)b * HEADS + h) * AGENT + a) * HD + dseg * 8) = v;
    }
}

// ---------------------------------------------------------------------------
// Q attention via MFMA + fused depthwise conv, IN-PLACE over q.
// grid = (b,h,half): 768 blocks, 4 waves; wave owns 16-row tiles stride 4.
// B operands (ahp*scale, agv) in registers; P transposed via per-wave LDS.
// S:  S[n][a] = q[n,:]·(ahp[a,:]*scale)   (A=q rows, Bt=ahp)
// PV: O[n][d] = P[n,:]·agv[:,d]           (A=P via LDS, Bt-frag = agv[a][d])
// C layout (verified in gemm_mfma): row=(lane>>4)*4+reg, col=lane&15 (+nf*16)
// ---------------------------------------------------------------------------
__global__ __launch_bounds__(256) void q_attn_mfma(
    bf16* qpre, const bf16* __restrict__ kv_own,
    const float* __restrict__ ahp_x, const bf16* __restrict__ ab_x,
    const bf16* __restrict__ agv_x,
    const float* __restrict__ dwc_w, const float* __restrict__ dwc_b)
{
    __shared__ short pL[4][16][72];   // per-wave P buffer (pad 72: 2-way banks)
    __shared__ float wS[9][64];
    __shared__ float cbS[64];

    int blk = blockIdx.x;
    int half = blk & 1;
    int h = (blk >> 1) % HEADS;
    int b = blk / (2 * HEADS);
    int tid = threadIdx.x;
    int wave = tid >> 6, lane = tid & 63;
    int acol = lane & 15, kgrp = lane >> 4;

    for (int i = tid; i < 9 * 64; i += 256)
        wS[i >> 6][i & 63] = dwc_w[(i >> 6) * DIM + h * HD + (i & 63)];
    if (tid < 64) cbS[tid] = dwc_b[h * HD + tid];
    for (int i = tid; i < 4 * 16 * 72; i += 256)
        ((short*)pL)[i] = 0;

    // B-frags for S: bs[ks][nf][i] = bf16(ahp[a][d]*scale), a=nf*16+acol,
    // d=ks*32+kgrp*8+i; zero for a>=49
    short8v bs[2][4];
#pragma unroll
    for (int ks = 0; ks < 2; ++ks)
#pragma unroll
        for (int nf = 0; nf < 4; ++nf) {
            int a = nf * 16 + acol;
            short8v v = {};
            if (a < AGENT) {
                const float* src = ahp_x + ((size_t)b * AGENT + a) * DIM + h * HD + ks * 32 + kgrp * 8;
                float4 r0 = *reinterpret_cast<const float4*>(src);
                float4 r1 = *reinterpret_cast<const float4*>(src + 4);
                v[0] = (short)f2bf(r0.x * SCALE); v[1] = (short)f2bf(r0.y * SCALE);
                v[2] = (short)f2bf(r0.z * SCALE); v[3] = (short)f2bf(r0.w * SCALE);
                v[4] = (short)f2bf(r1.x * SCALE); v[5] = (short)f2bf(r1.y * SCALE);
                v[6] = (short)f2bf(r1.z * SCALE); v[7] = (short)f2bf(r1.w * SCALE);
            }
            bs[ks][nf] = v;
        }

    // B-frags for PV: bv[ks][nf][i] = agv[a][d], a=ks*32+kgrp*8+i, d=nf*16+acol
    const short* agvs = (const short*)agv_x;
    short8v bv[2][4];
#pragma unroll
    for (int ks = 0; ks < 2; ++ks)
#pragma unroll
        for (int nf = 0; nf < 4; ++nf) {
            int d = nf * 16 + acol;
            short8v v = {};
#pragma unroll
            for (int i = 0; i < 8; ++i) {
                int a = ks * 32 + kgrp * 8 + i;
                if (a < AGENT)
                    v[i] = agvs[(((size_t)b * HEADS + h) * AGENT + a) * HD + d];
            }
            bv[ks][nf] = v;
        }

    __syncthreads();   // wS/cbS/pL-zeros visible; no further block-wide syncs

    int tstart = half ? 25 : 0, tend = half ? 49 : 25;
    for (int t = tstart + wave; t < tend; t += 4) {
        int n0 = t * 16;
        // A-frags: q rows (row=acol, k=kgrp*8+i, ks*32)
        const short* qrow = (const short*)qpre +
            ((size_t)(b * NPOS + n0 + acol)) * DIM + h * HD + kgrp * 8;
        short8v a0 = *reinterpret_cast<const short8v*>(qrow);
        short8v a1 = *reinterpret_cast<const short8v*>(qrow + 32);

        f32x4 accs[4] = {};
#pragma unroll
        for (int nf = 0; nf < 4; ++nf) {
            accs[nf] = __builtin_amdgcn_mfma_f32_16x16x32_bf16(a0, bs[0][nf], accs[nf], 0, 0, 0);
            accs[nf] = __builtin_amdgcn_mfma_f32_16x16x32_bf16(a1, bs[1][nf], accs[nf], 0, 0, 0);
        }

        // bias + mask + row softmax on C frags; write P (bf16) to pL
        float inv[4];
#pragma unroll
        for (int r = 0; r < 4; ++r) {
            int n = n0 + kgrp * 4 + r;
            float sarr[4];
            float m = -1e30f;
#pragma unroll
            for (int nf = 0; nf < 4; ++nf) {
                int a = nf * 16 + acol;
                float s = -1e30f;
                if (a < AGENT)
                    s = accs[nf][r] + bf2f(ab_x[((size_t)h * NPOS + n) * AGENT + a]);
                sarr[nf] = s;
                m = fmaxf(m, s);
            }
#pragma unroll
            for (int off = 1; off < 16; off <<= 1)
                m = fmaxf(m, __shfl_xor(m, off));
            float ls = 0.f;
#pragma unroll
            for (int nf = 0; nf < 4; ++nf) {
                float p = (sarr[nf] > -1e29f) ? __expf(sarr[nf] - m) : 0.f;
                sarr[nf] = p;
                ls += p;
            }
#pragma unroll
            for (int off = 1; off < 16; off <<= 1)
                ls += __shfl_xor(ls, off);
            inv[r] = 1.f / ls;
#pragma unroll
            for (int nf = 0; nf < 4; ++nf) {
                int a = nf * 16 + acol;
                if (a < AGENT)
                    pL[wave][kgrp * 4 + r][a] = (short)f2bf(sarr[nf]);
            }
        }

        // P A-frags (row=acol, k=kgrp*8+i); cols 49..63 are persistent zeros
        short8v p0 = *reinterpret_cast<const short8v*>(&pL[wave][acol][kgrp * 8]);
        short8v p1 = *reinterpret_cast<const short8v*>(&pL[wave][acol][kgrp * 8 + 32]);

        f32x4 acco[4] = {};
#pragma unroll
        for (int nf = 0; nf < 4; ++nf) {
            acco[nf] = __builtin_amdgcn_mfma_f32_16x16x32_bf16(p0, bv[0][nf], acco[nf], 0, 0, 0);
            acco[nf] = __builtin_amdgcn_mfma_f32_16x16x32_bf16(p1, bv[1][nf], acco[nf], 0, 0, 0);
        }

        // epilogue: divide by row-sum, add depthwise conv, store
#pragma unroll
        for (int r = 0; r < 4; ++r) {
            int n = n0 + kgrp * 4 + r;
            int i = n / WW, j = n % WW;
#pragma unroll
            for (int nf = 0; nf < 4; ++nf) {
                int d = nf * 16 + acol;
                float conv = cbS[d];
#pragma unroll
                for (int di = -1; di <= 1; ++di) {
                    int ii = i + di;
                    if (ii < 0 || ii >= HH) continue;
#pragma unroll
                    for (int dj = -1; dj <= 1; ++dj) {
                        int jj = j + dj;
                        if (jj < 0 || jj >= WW) continue;
                        conv += wS[(di + 1) * 3 + (dj + 1)][d] *
                                bf2f(kv_own[((size_t)(b * NPOS + ii * WW + jj)) * (2 * DIM) + DIM + h * HD + d]);
                    }
                }
                float o = acco[nf][r] * inv[r] + conv;
                qpre[((size_t)(b * NPOS + n)) * DIM + h * HD + d] = __float2bfloat16(o);
            }
        }
    }
}

// ---------------------------------------------------------------------------
extern "C" void kernel_launch(void* const* d_in, const int* in_sizes, int n_in,
                              void* d_out, int out_size, void* d_ws, size_t ws_size,
                              hipStream_t stream)
{
    const float* rgb_fea    = (const float*)d_in[0];
    const float* depth_fea  = (const float*)d_in[1];
    const float* rgb_q_w    = (const float*)d_in[2];
    const float* rgb_kv_w   = (const float*)d_in[3];
    const float* rgb_proj_w = (const float*)d_in[4];
    const float* rgb_proj_b = (const float*)d_in[5];
    const float* depth_q_w    = (const float*)d_in[6];
    const float* depth_kv_w   = (const float*)d_in[7];
    const float* depth_proj_w = (const float*)d_in[8];
    const float* depth_proj_b = (const float*)d_in[9];
    const float* rgb_dwc_w   = (const float*)d_in[10];
    const float* rgb_dwc_b   = (const float*)d_in[11];
    const float* depth_dwc_w = (const float*)d_in[12];
    const float* depth_dwc_b = (const float*)d_in[13];
    const float* rgb_an   = (const float*)d_in[14];
    const float* rgb_na   = (const float*)d_in[15];
    const float* rgb_ah_b = (const float*)d_in[16];
    const float* rgb_aw_b = (const float*)d_in[17];
    const float* rgb_ha_b = (const float*)d_in[18];
    const float* rgb_wa_b = (const float*)d_in[19];
    const float* depth_an   = (const float*)d_in[20];
    const float* depth_na   = (const float*)d_in[21];
    const float* depth_ah_b = (const float*)d_in[22];
    const float* depth_aw_b = (const float*)d_in[23];
    const float* depth_ha_b = (const float*)d_in[24];
    const float* depth_wa_b = (const float*)d_in[25];

    char* ws = (char*)d_ws;
    size_t off = 0;
    auto alloc = [&](size_t bytes) -> void* {
        void* p = ws + off;
        off += (bytes + 255) & ~(size_t)255;
        return p;
    };
    bf16* rgb_q    = (bf16*)alloc((size_t)MROWS * DIM * 2);
    bf16* depth_q  = (bf16*)alloc((size_t)MROWS * DIM * 2);
    bf16* rgb_kv   = (bf16*)alloc((size_t)MROWS * 2 * DIM * 2);
    bf16* depth_kv = (bf16*)alloc((size_t)MROWS * 2 * DIM * 2);
    bf16* rgb_pb    = (bf16*)alloc((size_t)HEADS * AGENT * NPOS * 2);
    bf16* depth_pb  = (bf16*)alloc((size_t)HEADS * AGENT * NPOS * 2);
    bf16* rgb_ab    = (bf16*)alloc((size_t)HEADS * NPOS * AGENT * 2);
    bf16* depth_ab  = (bf16*)alloc((size_t)HEADS * NPOS * AGENT * 2);
    bf16* rgb_agv   = (bf16*)alloc((size_t)BATCH * HEADS * AGENT * HD * 2);
    bf16* depth_agv = (bf16*)alloc((size_t)BATCH * HEADS * AGENT * HD * 2);
    bf16* proj_wt_r = (bf16*)alloc((size_t)DIM * DIM * 2);
    bf16* proj_wt_d = (bf16*)alloc((size_t)DIM * DIM * 2);
    size_t ubase = off;
    bf16* q_wt_r  = (bf16*)alloc((size_t)DIM * DIM * 2);
    bf16* kv_wt_r = (bf16*)alloc((size_t)DIM * 2 * DIM * 2);
    bf16* q_wt_d  = (bf16*)alloc((size_t)DIM * DIM * 2);
    bf16* kv_wt_d = (bf16*)alloc((size_t)DIM * 2 * DIM * 2);
    off = ubase;  // alias
    float* rgb_ahp   = (float*)alloc((size_t)BATCH * AGENT * DIM * 4);
    float* depth_ahp = (float*)alloc((size_t)BATCH * AGENT * DIM * 4);

    dim3 blk(256);

    // 0) weight transposes (f32 [K][N] -> bf16 [N][K])
    transpose_w_bf16<<<dim3(24, 24), blk, 0, stream>>>(rgb_q_w, q_wt_r, DIM, DIM);
    transpose_w_bf16<<<dim3(48, 24), blk, 0, stream>>>(rgb_kv_w, kv_wt_r, DIM, 2 * DIM);
    transpose_w_bf16<<<dim3(24, 24), blk, 0, stream>>>(depth_q_w, q_wt_d, DIM, DIM);
    transpose_w_bf16<<<dim3(48, 24), blk, 0, stream>>>(depth_kv_w, kv_wt_d, DIM, 2 * DIM);
    transpose_w_bf16<<<dim3(24, 24), blk, 0, stream>>>(rgb_proj_w, proj_wt_r, DIM, DIM);
    transpose_w_bf16<<<dim3(24, 24), blk, 0, stream>>>(depth_proj_w, proj_wt_d, DIM, DIM);

    // 1) q / kv projections
    gemm_mfma<true, false><<<dim3(6, 196), blk, 0, stream>>>(rgb_fea, q_wt_r, nullptr, rgb_q, MROWS, DIM, DIM);
    gemm_mfma<true, false><<<dim3(6, 196), blk, 0, stream>>>(depth_fea, q_wt_d, nullptr, depth_q, MROWS, DIM, DIM);
    gemm_mfma<true, false><<<dim3(12, 196), blk, 0, stream>>>(rgb_fea, kv_wt_r, nullptr, rgb_kv, MROWS, 2 * DIM, DIM);
    gemm_mfma<true, false><<<dim3(12, 196), blk, 0, stream>>>(depth_fea, kv_wt_d, nullptr, depth_kv, MROWS, 2 * DIM, DIM);

    // 2) agent pooling of q
    pool_kernel<<<(BATCH * AGENT * DIM + 255) / 256, blk, 0, stream>>>(rgb_q, rgb_ahp);
    pool_kernel<<<(BATCH * AGENT * DIM + 255) / 256, blk, 0, stream>>>(depth_q, depth_ahp);

    // 3) position biases
    pos_bias_kernel<<<(HEADS * AGENT * NPOS + 255) / 256, blk, 0, stream>>>(rgb_an, rgb_ah_b, rgb_aw_b, rgb_pb);
    pos_bias_kernel<<<(HEADS * AGENT * NPOS + 255) / 256, blk, 0, stream>>>(depth_an, depth_ah_b, depth_aw_b, depth_pb);
    ag_bias_kernel<<<(HEADS * NPOS * AGENT + 255) / 256, blk, 0, stream>>>(rgb_na, rgb_ha_b, rgb_wa_b, rgb_ab);
    ag_bias_kernel<<<(HEADS * NPOS * AGENT + 255) / 256, blk, 0, stream>>>(depth_na, depth_ha_b, depth_wa_b, depth_ab);

    // 4) cross-modal agent aggregation
    agent_attn2<<<BATCH * HEADS, blk, 0, stream>>>(depth_ahp, rgb_kv, rgb_pb, depth_agv);
    agent_attn2<<<BATCH * HEADS, blk, 0, stream>>>(rgb_ahp, depth_kv, depth_pb, rgb_agv);

    // 5) agent broadcast (MFMA) + fused depthwise conv (in-place q -> pre)
    q_attn_mfma<<<BATCH * HEADS * 2, blk, 0, stream>>>(rgb_q, rgb_kv, depth_ahp, depth_ab, depth_agv,
                                                       rgb_dwc_w, rgb_dwc_b);
    q_attn_mfma<<<BATCH * HEADS * 2, blk, 0, stream>>>(depth_q, depth_kv, rgb_ahp, rgb_ab, rgb_agv,
                                                       depth_dwc_w, depth_dwc_b);

    // 6) output projections
    float* out = (float*)d_out;
    gemm_mfma<false, true><<<dim3(6, 196), blk, 0, stream>>>(rgb_q, proj_wt_r, rgb_proj_b, out, MROWS, DIM, DIM);
    gemm_mfma<false, true><<<dim3(6, 196), blk, 0, stream>>>(depth_q, proj_wt_d, depth_proj_b,
                                                             out + (size_t)MROWS * DIM, MROWS, DIM, DIM);
}

// Round 7
// 1126.903 us; speedup vs baseline: 6.0340x; 1.3200x over previous
//
#include <hip/hip_runtime.h>
#include <hip/hip_bf16.h>

#define BATCH 32
#define NPOS 784
#define DIM 768
#define HEADS 12
#define HD 64
#define AGENT 49
#define HH 28
#define WW 28
#define MROWS (BATCH*NPOS)   // 25088
#define SCALE 0.125f

using bf16 = __hip_bfloat16;
typedef __attribute__((ext_vector_type(4))) float f32x4;
typedef __attribute__((ext_vector_type(8))) short short8v;

__device__ __forceinline__ float bf2f(bf16 x) { return __bfloat162float(x); }
__device__ __forceinline__ float bfs2f(short s) {
    unsigned int u = ((unsigned int)(unsigned short)s) << 16;
    return __uint_as_float(u);
}
__device__ __forceinline__ unsigned short f2bf(float x) {
    unsigned int u = __float_as_uint(x);
    unsigned int r = (u + 0x7fffu + ((u >> 16) & 1u)) >> 16;
    return (unsigned short)r;
}

// ---------------------------------------------------------------------------
// Transpose+convert: W [K][N] f32 -> Wt [N][K] bf16. 256 thr = 32x8.
// ---------------------------------------------------------------------------
__global__ __launch_bounds__(256) void transpose_w_bf16(
    const float* __restrict__ W, bf16* __restrict__ Wt, int K, int N)
{
    __shared__ float t[32][33];
    int tx = threadIdx.x & 31, ty = threadIdx.x >> 5;
    int k0 = blockIdx.y * 32, n0 = blockIdx.x * 32;
#pragma unroll
    for (int i = 0; i < 4; ++i)
        t[ty + 8 * i][tx] = W[(size_t)(k0 + ty + 8 * i) * N + n0 + tx];
    __syncthreads();
#pragma unroll
    for (int i = 0; i < 4; ++i)
        Wt[(size_t)(n0 + ty + 8 * i) * K + k0 + tx] = __float2bfloat16(t[tx][ty + 8 * i]);
}

// ---------------------------------------------------------------------------
// MFMA GEMM: C[M,N] = A[M,K] @ Bt[N,K]^T, bf16 MFMA, f32 accum.
// ---------------------------------------------------------------------------
template<bool AF32, bool OUTF32>
__global__ __launch_bounds__(256) void gemm_mfma(
    const void* __restrict__ Ap, const bf16* __restrict__ Bt,
    const float* __restrict__ bias, void* __restrict__ Cp,
    int M, int N, int K)
{
    __shared__ short As[128][40];
    __shared__ short Bs[128][40];
    int tid = threadIdx.x;
    int wave = tid >> 6, lane = tid & 63;
    int m0 = blockIdx.y * 128, n0 = blockIdx.x * 128;
    int wm = (wave >> 1) * 64, wn = (wave & 1) * 64;

    f32x4 acc[4][4] = {};

    const short* Ab = (const short*)Ap;
    const float* Af = (const float*)Ap;
    const short* Btb = (const short*)Bt;

    for (int k0 = 0; k0 < K; k0 += 32) {
        if constexpr (AF32) {
#pragma unroll
            for (int it = 0; it < 4; ++it) {
                int idx = tid + 256 * it;
                int row = idx >> 3, kp = (idx & 7) * 4;
                float4 v = *reinterpret_cast<const float4*>(
                    Af + (size_t)(m0 + row) * K + k0 + kp);
                unsigned int w0 = (unsigned int)f2bf(v.x) | ((unsigned int)f2bf(v.y) << 16);
                unsigned int w1 = (unsigned int)f2bf(v.z) | ((unsigned int)f2bf(v.w) << 16);
                uint2 pk; pk.x = w0; pk.y = w1;
                *reinterpret_cast<uint2*>(&As[row][kp]) = pk;
            }
        } else {
#pragma unroll
            for (int it = 0; it < 2; ++it) {
                int idx = tid + 256 * it;
                int row = idx >> 2, kp = (idx & 3) * 8;
                short8v v = *reinterpret_cast<const short8v*>(
                    Ab + (size_t)(m0 + row) * K + k0 + kp);
                *reinterpret_cast<short8v*>(&As[row][kp]) = v;
            }
        }
#pragma unroll
        for (int it = 0; it < 2; ++it) {
            int idx = tid + 256 * it;
            int row = idx >> 2, kp = (idx & 3) * 8;
            short8v v = *reinterpret_cast<const short8v*>(
                Btb + (size_t)(n0 + row) * K + k0 + kp);
            *reinterpret_cast<short8v*>(&Bs[row][kp]) = v;
        }
        __syncthreads();

        short8v af[4], bfr[4];
#pragma unroll
        for (int mf = 0; mf < 4; ++mf)
            af[mf] = *reinterpret_cast<const short8v*>(
                &As[wm + mf * 16 + (lane & 15)][(lane >> 4) * 8]);
#pragma unroll
        for (int nf = 0; nf < 4; ++nf)
            bfr[nf] = *reinterpret_cast<const short8v*>(
                &Bs[wn + nf * 16 + (lane & 15)][(lane >> 4) * 8]);
#pragma unroll
        for (int mf = 0; mf < 4; ++mf)
#pragma unroll
            for (int nf = 0; nf < 4; ++nf)
                acc[mf][nf] = __builtin_amdgcn_mfma_f32_16x16x32_bf16(
                    af[mf], bfr[nf], acc[mf][nf], 0, 0, 0);
        __syncthreads();
    }

    int rgrp = (lane >> 4) * 4, cidx = lane & 15;
#pragma unroll
    for (int mf = 0; mf < 4; ++mf)
#pragma unroll
        for (int nf = 0; nf < 4; ++nf)
#pragma unroll
            for (int r = 0; r < 4; ++r) {
                int row = m0 + wm + mf * 16 + rgrp + r;
                int col = n0 + wn + nf * 16 + cidx;
                float v = acc[mf][nf][r];
                if constexpr (OUTF32)
                    ((float*)Cp)[(size_t)row * N + col] = v + bias[col];
                else
                    ((bf16*)Cp)[(size_t)row * N + col] = __float2bfloat16(v);
            }
}

// ---------------------------------------------------------------------------
// Pool: ahp[b][a][c] = mean over 4x4 block of q[b][n][c]  (bf16 in, f32 out)
// ---------------------------------------------------------------------------
__global__ void pool_kernel(const bf16* __restrict__ q, float* __restrict__ ahp)
{
    int idx = blockIdx.x * 256 + threadIdx.x;
    if (idx >= BATCH * AGENT * DIM) return;
    int c = idx % DIM;
    int a = (idx / DIM) % AGENT;
    int b = idx / (DIM * AGENT);
    int ai = a / 7, aj = a % 7;
    float s = 0.f;
#pragma unroll
    for (int u = 0; u < 4; ++u)
#pragma unroll
        for (int v = 0; v < 4; ++v) {
            int n = (ai * 4 + u) * WW + (aj * 4 + v);
            s += bf2f(q[((size_t)b * NPOS + n) * DIM + c]);
        }
    ahp[idx] = s * (1.f / 16.f);
}

// ---------------------------------------------------------------------------
// Bilinear 7->28 upsample, half-pixel centers, edge clamp
// ---------------------------------------------------------------------------
__device__ __forceinline__ float bilerp7(const float* __restrict__ img, int i, int j)
{
    float si = 0.25f * i - 0.375f, sj = 0.25f * j - 0.375f;
    int i0 = (int)floorf(si); float fi = si - i0;
    int j0 = (int)floorf(sj); float fj = sj - j0;
    int i0c = min(max(i0, 0), 6), i1c = min(max(i0 + 1, 0), 6);
    int j0c = min(max(j0, 0), 6), j1c = min(max(j0 + 1, 0), 6);
    float v00 = img[i0c * 7 + j0c], v01 = img[i0c * 7 + j1c];
    float v10 = img[i1c * 7 + j0c], v11 = img[i1c * 7 + j1c];
    return (1.f - fi) * ((1.f - fj) * v00 + fj * v01) + fi * ((1.f - fj) * v10 + fj * v11);
}

__global__ void pos_bias_kernel(const float* __restrict__ an, const float* __restrict__ ah_b,
                                const float* __restrict__ aw_b, bf16* __restrict__ pb)
{
    int idx = blockIdx.x * 256 + threadIdx.x;
    if (idx >= HEADS * AGENT * NPOS) return;
    int n = idx % NPOS;
    int a = (idx / NPOS) % AGENT;
    int h = idx / (NPOS * AGENT);
    int i = n / WW, j = n % WW;
    float v = bilerp7(an + (size_t)(h * AGENT + a) * 49, i, j);
    v += ah_b[(h * AGENT + a) * HH + i] + aw_b[(h * AGENT + a) * WW + j];
    pb[idx] = __float2bfloat16(v);
}

__global__ void ag_bias_kernel(const float* __restrict__ na, const float* __restrict__ ha_b,
                               const float* __restrict__ wa_b, bf16* __restrict__ ab)
{
    int idx = blockIdx.x * 256 + threadIdx.x;
    if (idx >= HEADS * NPOS * AGENT) return;
    int a = idx % AGENT;
    int n = (idx / AGENT) % NPOS;
    int h = idx / (AGENT * NPOS);
    int i = n / WW, j = n % WW;
    float v = bilerp7(na + (size_t)(h * AGENT + a) * 49, i, j);
    v += ha_b[(h * HH + i) * AGENT + a] + wa_b[(h * WW + j) * AGENT + a];
    ab[idx] = __float2bfloat16(v);
}

// ---------------------------------------------------------------------------
// Agent attention v3 (full MFMA): one block per (b,h), 4 waves.
// Wave owns n-tiles of 64 (t = wave, wave+4, ... < 13; tail tile 12 has 16
// valid cols). Per tile:
//   S'[a][n] = (q*scale) @ K^T  : A=q agents (reg), B-frag = contiguous K-row
//   online softmax on C-frags   : in-lane over nf + shfl_xor over 16-lane col
//   PV: O[a][d] += P @ V        : P via per-wave pL[a][n], V via VtL[d][n]
// Flash merge of 4 wave-partials through aliased LDS (Om over pL/VtL).
// ---------------------------------------------------------------------------
__global__ __launch_bounds__(256, 2) void agent_attn3(
    const float* __restrict__ ahp, const bf16* __restrict__ kv,
    const bf16* __restrict__ pb, bf16* __restrict__ agent_v)
{
    __shared__ __align__(16) char smem[75776];
    short (*pL)[64][72]  = (short (*)[64][72])smem;            // [4][64][72]
    short (*VtL)[64][72] = (short (*)[64][72])(smem + 36864);  // [4][64][72]
    float (*Om)[64][66]  = (float (*)[64][66])smem;            // [4][64][66] (aliases pL/VtL)
    float (*mw)[64]      = (float (*)[64])(smem + 73728);
    float (*lw)[64]      = (float (*)[64])(smem + 74752);

    int tid = threadIdx.x;
    int wave = tid >> 6, lane = tid & 63;
    int acol = lane & 15, kgrp = lane >> 4;
    int h = blockIdx.x % HEADS;
    int b = blockIdx.x / HEADS;
    const short* kvs = (const short*)kv;
    const bf16* pbh = pb + (size_t)h * AGENT * NPOS;

    // A-frags: q agents * SCALE (a = mf*16+acol, k=d = ks*32+kgrp*8+i)
    short8v qa[2][4];
#pragma unroll
    for (int ks = 0; ks < 2; ++ks)
#pragma unroll
        for (int mf = 0; mf < 4; ++mf) {
            int a = mf * 16 + acol;
            short8v v = {};
            if (a < AGENT) {
                const float* src = ahp + ((size_t)b * AGENT + a) * DIM + h * HD + ks * 32 + kgrp * 8;
                float4 r0 = *reinterpret_cast<const float4*>(src);
                float4 r1 = *reinterpret_cast<const float4*>(src + 4);
                v[0] = (short)f2bf(r0.x * SCALE); v[1] = (short)f2bf(r0.y * SCALE);
                v[2] = (short)f2bf(r0.z * SCALE); v[3] = (short)f2bf(r0.w * SCALE);
                v[4] = (short)f2bf(r1.x * SCALE); v[5] = (short)f2bf(r1.y * SCALE);
                v[6] = (short)f2bf(r1.z * SCALE); v[7] = (short)f2bf(r1.w * SCALE);
            }
            qa[ks][mf] = v;
        }

    float mrun[16], lrun[16];
#pragma unroll
    for (int i = 0; i < 16; ++i) { mrun[i] = -1e30f; lrun[i] = 0.f; }
    f32x4 accO[4][4] = {};

    for (int t = wave; t < 13; t += 4) {
        int n0 = t * 64;

        // ---- stage V tile transposed: VtL[d][nloc] (pair-packed b32 writes)
        {
            int p = lane & 31, dh = lane >> 5;
            const short* v0p = kvs + (size_t)(b * NPOS + n0 + 2 * p) * (2 * DIM) + DIM + h * HD + dh * 32;
#pragma unroll
            for (int s = 0; s < 4; ++s) {
                short8v va = {}, vb = {};
                if (n0 + 2 * p < NPOS)     va = *reinterpret_cast<const short8v*>(v0p + s * 8);
                if (n0 + 2 * p + 1 < NPOS) vb = *reinterpret_cast<const short8v*>(v0p + 2 * DIM + s * 8);
#pragma unroll
                for (int u = 0; u < 8; ++u) {
                    int d = dh * 32 + s * 8 + u;
                    unsigned int w = ((unsigned int)(unsigned short)va[u]) |
                                     (((unsigned int)(unsigned short)vb[u]) << 16);
                    *reinterpret_cast<unsigned int*>(&VtL[wave][d][2 * p]) = w;
                }
            }
        }

        // ---- K B-frags: contiguous 16B global loads (col=n, k=d)
        short8v kb[2][4];
#pragma unroll
        for (int nf = 0; nf < 4; ++nf) {
            int n = n0 + nf * 16 + acol;
            bool val = (n < NPOS);
            const short* kp = kvs + (size_t)(b * NPOS + n) * (2 * DIM) + h * HD + kgrp * 8;
#pragma unroll
            for (int ks = 0; ks < 2; ++ks) {
                short8v v = {};
                if (val) v = *reinterpret_cast<const short8v*>(kp + ks * 32);
                kb[ks][nf] = v;
            }
        }

        // ---- S' MFMA
        f32x4 accS[4][4] = {};
#pragma unroll
        for (int mf = 0; mf < 4; ++mf)
#pragma unroll
            for (int nf = 0; nf < 4; ++nf) {
                accS[mf][nf] = __builtin_amdgcn_mfma_f32_16x16x32_bf16(qa[0][mf], kb[0][nf], accS[mf][nf], 0, 0, 0);
                accS[mf][nf] = __builtin_amdgcn_mfma_f32_16x16x32_bf16(qa[1][mf], kb[1][nf], accS[mf][nf], 0, 0, 0);
            }

        // ---- bias + mask + online softmax, write P to pL
#pragma unroll
        for (int mf = 0; mf < 4; ++mf)
#pragma unroll
            for (int r = 0; r < 4; ++r) {
                int a = mf * 16 + kgrp * 4 + r;
                float s[4];
                float mt = -1e30f;
#pragma unroll
                for (int nf = 0; nf < 4; ++nf) {
                    int n = n0 + nf * 16 + acol;
                    float sv = -1e30f;
                    if (n < NPOS) {
                        sv = accS[mf][nf][r];
                        if (a < AGENT) sv += bf2f(pbh[(size_t)a * NPOS + n]);
                    }
                    s[nf] = sv;
                    mt = fmaxf(mt, sv);
                }
#pragma unroll
                for (int off = 1; off < 16; off <<= 1)
                    mt = fmaxf(mt, __shfl_xor(mt, off));
                float mnew = fmaxf(mrun[mf * 4 + r], mt);
                float fac = __expf(mrun[mf * 4 + r] - mnew);
                float ps = 0.f;
#pragma unroll
                for (int nf = 0; nf < 4; ++nf) {
                    float pv = (s[nf] > -1e29f) ? __expf(s[nf] - mnew) : 0.f;
                    ps += pv;
                    pL[wave][a][nf * 16 + acol] = (short)f2bf(pv);
                }
#pragma unroll
                for (int off = 1; off < 16; off <<= 1)
                    ps += __shfl_xor(ps, off);
                mrun[mf * 4 + r] = mnew;
                lrun[mf * 4 + r] = lrun[mf * 4 + r] * fac + ps;
#pragma unroll
                for (int df = 0; df < 4; ++df) accO[mf][df][r] *= fac;
            }

        // ---- PV MFMA: A = P rows (pL), B = V cols (VtL)
        short8v vb2[2][4];
#pragma unroll
        for (int ks = 0; ks < 2; ++ks)
#pragma unroll
            for (int df = 0; df < 4; ++df)
                vb2[ks][df] = *reinterpret_cast<const short8v*>(
                    &VtL[wave][df * 16 + acol][ks * 32 + kgrp * 8]);
#pragma unroll
        for (int mf = 0; mf < 4; ++mf) {
#pragma unroll
            for (int ks = 0; ks < 2; ++ks) {
                short8v pa = *reinterpret_cast<const short8v*>(
                    &pL[wave][mf * 16 + acol][ks * 32 + kgrp * 8]);
#pragma unroll
                for (int df = 0; df < 4; ++df)
                    accO[mf][df] = __builtin_amdgcn_mfma_f32_16x16x32_bf16(pa, vb2[ks][df], accO[mf][df], 0, 0, 0);
            }
        }
    }

    // ---- write wave-partial m/l, then O (Om aliases pL/VtL -> barrier first)
    if (acol == 0) {
#pragma unroll
        for (int mf = 0; mf < 4; ++mf)
#pragma unroll
            for (int r = 0; r < 4; ++r) {
                mw[wave][mf * 16 + kgrp * 4 + r] = mrun[mf * 4 + r];
                lw[wave][mf * 16 + kgrp * 4 + r] = lrun[mf * 4 + r];
            }
    }
    __syncthreads();
#pragma unroll
    for (int mf = 0; mf < 4; ++mf)
#pragma unroll
        for (int df = 0; df < 4; ++df)
#pragma unroll
            for (int r = 0; r < 4; ++r)
                Om[wave][mf * 16 + kgrp * 4 + r][df * 16 + acol] = accO[mf][df][r];
    __syncthreads();

    // ---- merge 4 wave-partials
    for (int idx = tid; idx < AGENT * HD; idx += 256) {
        int a = idx >> 6, d = idx & 63;
        float m = fmaxf(fmaxf(mw[0][a], mw[1][a]), fmaxf(mw[2][a], mw[3][a]));
        float l = 0.f, o = 0.f;
#pragma unroll
        for (int w = 0; w < 4; ++w) {
            float f = __expf(mw[w][a] - m);
            l += f * lw[w][a];
            o += f * Om[w][a][d];
        }
        ((short*)agent_v)[(((size_t)b * HEADS + h) * AGENT + a) * HD + d] = (short)f2bf(o / l);
    }
}

// ---------------------------------------------------------------------------
// Q attention via MFMA + fused depthwise conv, IN-PLACE over q. (unchanged)
// ---------------------------------------------------------------------------
__global__ __launch_bounds__(256) void q_attn_mfma(
    bf16* qpre, const bf16* __restrict__ kv_own,
    const float* __restrict__ ahp_x, const bf16* __restrict__ ab_x,
    const bf16* __restrict__ agv_x,
    const float* __restrict__ dwc_w, const float* __restrict__ dwc_b)
{
    __shared__ short pL[4][16][72];
    __shared__ float wS[9][64];
    __shared__ float cbS[64];

    int blk = blockIdx.x;
    int half = blk & 1;
    int h = (blk >> 1) % HEADS;
    int b = blk / (2 * HEADS);
    int tid = threadIdx.x;
    int wave = tid >> 6, lane = tid & 63;
    int acol = lane & 15, kgrp = lane >> 4;

    for (int i = tid; i < 9 * 64; i += 256)
        wS[i >> 6][i & 63] = dwc_w[(i >> 6) * DIM + h * HD + (i & 63)];
    if (tid < 64) cbS[tid] = dwc_b[h * HD + tid];
    for (int i = tid; i < 4 * 16 * 72; i += 256)
        ((short*)pL)[i] = 0;

    short8v bs[2][4];
#pragma unroll
    for (int ks = 0; ks < 2; ++ks)
#pragma unroll
        for (int nf = 0; nf < 4; ++nf) {
            int a = nf * 16 + acol;
            short8v v = {};
            if (a < AGENT) {
                const float* src = ahp_x + ((size_t)b * AGENT + a) * DIM + h * HD + ks * 32 + kgrp * 8;
                float4 r0 = *reinterpret_cast<const float4*>(src);
                float4 r1 = *reinterpret_cast<const float4*>(src + 4);
                v[0] = (short)f2bf(r0.x * SCALE); v[1] = (short)f2bf(r0.y * SCALE);
                v[2] = (short)f2bf(r0.z * SCALE); v[3] = (short)f2bf(r0.w * SCALE);
                v[4] = (short)f2bf(r1.x * SCALE); v[5] = (short)f2bf(r1.y * SCALE);
                v[6] = (short)f2bf(r1.z * SCALE); v[7] = (short)f2bf(r1.w * SCALE);
            }
            bs[ks][nf] = v;
        }

    const short* agvs = (const short*)agv_x;
    short8v bv[2][4];
#pragma unroll
    for (int ks = 0; ks < 2; ++ks)
#pragma unroll
        for (int nf = 0; nf < 4; ++nf) {
            int d = nf * 16 + acol;
            short8v v = {};
#pragma unroll
            for (int i = 0; i < 8; ++i) {
                int a = ks * 32 + kgrp * 8 + i;
                if (a < AGENT)
                    v[i] = agvs[(((size_t)b * HEADS + h) * AGENT + a) * HD + d];
            }
            bv[ks][nf] = v;
        }

    __syncthreads();

    int tstart = half ? 25 : 0, tend = half ? 49 : 25;
    for (int t = tstart + wave; t < tend; t += 4) {
        int n0 = t * 16;
        const short* qrow = (const short*)qpre +
            ((size_t)(b * NPOS + n0 + acol)) * DIM + h * HD + kgrp * 8;
        short8v a0 = *reinterpret_cast<const short8v*>(qrow);
        short8v a1 = *reinterpret_cast<const short8v*>(qrow + 32);

        f32x4 accs[4] = {};
#pragma unroll
        for (int nf = 0; nf < 4; ++nf) {
            accs[nf] = __builtin_amdgcn_mfma_f32_16x16x32_bf16(a0, bs[0][nf], accs[nf], 0, 0, 0);
            accs[nf] = __builtin_amdgcn_mfma_f32_16x16x32_bf16(a1, bs[1][nf], accs[nf], 0, 0, 0);
        }

        float inv[4];
#pragma unroll
        for (int r = 0; r < 4; ++r) {
            int n = n0 + kgrp * 4 + r;
            float sarr[4];
            float m = -1e30f;
#pragma unroll
            for (int nf = 0; nf < 4; ++nf) {
                int a = nf * 16 + acol;
                float s = -1e30f;
                if (a < AGENT)
                    s = accs[nf][r] + bf2f(ab_x[((size_t)h * NPOS + n) * AGENT + a]);
                sarr[nf] = s;
                m = fmaxf(m, s);
            }
#pragma unroll
            for (int off = 1; off < 16; off <<= 1)
                m = fmaxf(m, __shfl_xor(m, off));
            float ls = 0.f;
#pragma unroll
            for (int nf = 0; nf < 4; ++nf) {
                float p = (sarr[nf] > -1e29f) ? __expf(sarr[nf] - m) : 0.f;
                sarr[nf] = p;
                ls += p;
            }
#pragma unroll
            for (int off = 1; off < 16; off <<= 1)
                ls += __shfl_xor(ls, off);
            inv[r] = 1.f / ls;
#pragma unroll
            for (int nf = 0; nf < 4; ++nf) {
                int a = nf * 16 + acol;
                if (a < AGENT)
                    pL[wave][kgrp * 4 + r][a] = (short)f2bf(sarr[nf]);
            }
        }

        short8v p0 = *reinterpret_cast<const short8v*>(&pL[wave][acol][kgrp * 8]);
        short8v p1 = *reinterpret_cast<const short8v*>(&pL[wave][acol][kgrp * 8 + 32]);

        f32x4 acco[4] = {};
#pragma unroll
        for (int nf = 0; nf < 4; ++nf) {
            acco[nf] = __builtin_amdgcn_mfma_f32_16x16x32_bf16(p0, bv[0][nf], acco[nf], 0, 0, 0);
            acco[nf] = __builtin_amdgcn_mfma_f32_16x16x32_bf16(p1, bv[1][nf], acco[nf], 0, 0, 0);
        }

#pragma unroll
        for (int r = 0; r < 4; ++r) {
            int n = n0 + kgrp * 4 + r;
            int i = n / WW, j = n % WW;
#pragma unroll
            for (int nf = 0; nf < 4; ++nf) {
                int d = nf * 16 + acol;
                float conv = cbS[d];
#pragma unroll
                for (int di = -1; di <= 1; ++di) {
                    int ii = i + di;
                    if (ii < 0 || ii >= HH) continue;
#pragma unroll
                    for (int dj = -1; dj <= 1; ++dj) {
                        int jj = j + dj;
                        if (jj < 0 || jj >= WW) continue;
                        conv += wS[(di + 1) * 3 + (dj + 1)][d] *
                                bf2f(kv_own[((size_t)(b * NPOS + ii * WW + jj)) * (2 * DIM) + DIM + h * HD + d]);
                    }
                }
                float o = acco[nf][r] * inv[r] + conv;
                qpre[((size_t)(b * NPOS + n)) * DIM + h * HD + d] = __float2bfloat16(o);
            }
        }
    }
}

// ---------------------------------------------------------------------------
extern "C" void kernel_launch(void* const* d_in, const int* in_sizes, int n_in,
                              void* d_out, int out_size, void* d_ws, size_t ws_size,
                              hipStream_t stream)
{
    const float* rgb_fea    = (const float*)d_in[0];
    const float* depth_fea  = (const float*)d_in[1];
    const float* rgb_q_w    = (const float*)d_in[2];
    const float* rgb_kv_w   = (const float*)d_in[3];
    const float* rgb_proj_w = (const float*)d_in[4];
    const float* rgb_proj_b = (const float*)d_in[5];
    const float* depth_q_w    = (const float*)d_in[6];
    const float* depth_kv_w   = (const float*)d_in[7];
    const float* depth_proj_w = (const float*)d_in[8];
    const float* depth_proj_b = (const float*)d_in[9];
    const float* rgb_dwc_w   = (const float*)d_in[10];
    const float* rgb_dwc_b   = (const float*)d_in[11];
    const float* depth_dwc_w = (const float*)d_in[12];
    const float* depth_dwc_b = (const float*)d_in[13];
    const float* rgb_an   = (const float*)d_in[14];
    const float* rgb_na   = (const float*)d_in[15];
    const float* rgb_ah_b = (const float*)d_in[16];
    const float* rgb_aw_b = (const float*)d_in[17];
    const float* rgb_ha_b = (const float*)d_in[18];
    const float* rgb_wa_b = (const float*)d_in[19];
    const float* depth_an   = (const float*)d_in[20];
    const float* depth_na   = (const float*)d_in[21];
    const float* depth_ah_b = (const float*)d_in[22];
    const float* depth_aw_b = (const float*)d_in[23];
    const float* depth_ha_b = (const float*)d_in[24];
    const float* depth_wa_b = (const float*)d_in[25];

    char* ws = (char*)d_ws;
    size_t off = 0;
    auto alloc = [&](size_t bytes) -> void* {
        void* p = ws + off;
        off += (bytes + 255) & ~(size_t)255;
        return p;
    };
    bf16* rgb_q    = (bf16*)alloc((size_t)MROWS * DIM * 2);
    bf16* depth_q  = (bf16*)alloc((size_t)MROWS * DIM * 2);
    bf16* rgb_kv   = (bf16*)alloc((size_t)MROWS * 2 * DIM * 2);
    bf16* depth_kv = (bf16*)alloc((size_t)MROWS * 2 * DIM * 2);
    bf16* rgb_pb    = (bf16*)alloc((size_t)HEADS * AGENT * NPOS * 2);
    bf16* depth_pb  = (bf16*)alloc((size_t)HEADS * AGENT * NPOS * 2);
    bf16* rgb_ab    = (bf16*)alloc((size_t)HEADS * NPOS * AGENT * 2);
    bf16* depth_ab  = (bf16*)alloc((size_t)HEADS * NPOS * AGENT * 2);
    bf16* rgb_agv   = (bf16*)alloc((size_t)BATCH * HEADS * AGENT * HD * 2);
    bf16* depth_agv = (bf16*)alloc((size_t)BATCH * HEADS * AGENT * HD * 2);
    bf16* proj_wt_r = (bf16*)alloc((size_t)DIM * DIM * 2);
    bf16* proj_wt_d = (bf16*)alloc((size_t)DIM * DIM * 2);
    size_t ubase = off;
    bf16* q_wt_r  = (bf16*)alloc((size_t)DIM * DIM * 2);
    bf16* kv_wt_r = (bf16*)alloc((size_t)DIM * 2 * DIM * 2);
    bf16* q_wt_d  = (bf16*)alloc((size_t)DIM * DIM * 2);
    bf16* kv_wt_d = (bf16*)alloc((size_t)DIM * 2 * DIM * 2);
    off = ubase;  // alias
    float* rgb_ahp   = (float*)alloc((size_t)BATCH * AGENT * DIM * 4);
    float* depth_ahp = (float*)alloc((size_t)BATCH * AGENT * DIM * 4);

    dim3 blk(256);

    // 0) weight transposes (f32 [K][N] -> bf16 [N][K])
    transpose_w_bf16<<<dim3(24, 24), blk, 0, stream>>>(rgb_q_w, q_wt_r, DIM, DIM);
    transpose_w_bf16<<<dim3(48, 24), blk, 0, stream>>>(rgb_kv_w, kv_wt_r, DIM, 2 * DIM);
    transpose_w_bf16<<<dim3(24, 24), blk, 0, stream>>>(depth_q_w, q_wt_d, DIM, DIM);
    transpose_w_bf16<<<dim3(48, 24), blk, 0, stream>>>(depth_kv_w, kv_wt_d, DIM, 2 * DIM);
    transpose_w_bf16<<<dim3(24, 24), blk, 0, stream>>>(rgb_proj_w, proj_wt_r, DIM, DIM);
    transpose_w_bf16<<<dim3(24, 24), blk, 0, stream>>>(depth_proj_w, proj_wt_d, DIM, DIM);

    // 1) q / kv projections
    gemm_mfma<true, false><<<dim3(6, 196), blk, 0, stream>>>(rgb_fea, q_wt_r, nullptr, rgb_q, MROWS, DIM, DIM);
    gemm_mfma<true, false><<<dim3(6, 196), blk, 0, stream>>>(depth_fea, q_wt_d, nullptr, depth_q, MROWS, DIM, DIM);
    gemm_mfma<true, false><<<dim3(12, 196), blk, 0, stream>>>(rgb_fea, kv_wt_r, nullptr, rgb_kv, MROWS, 2 * DIM, DIM);
    gemm_mfma<true, false><<<dim3(12, 196), blk, 0, stream>>>(depth_fea, kv_wt_d, nullptr, depth_kv, MROWS, 2 * DIM, DIM);

    // 2) agent pooling of q
    pool_kernel<<<(BATCH * AGENT * DIM + 255) / 256, blk, 0, stream>>>(rgb_q, rgb_ahp);
    pool_kernel<<<(BATCH * AGENT * DIM + 255) / 256, blk, 0, stream>>>(depth_q, depth_ahp);

    // 3) position biases
    pos_bias_kernel<<<(HEADS * AGENT * NPOS + 255) / 256, blk, 0, stream>>>(rgb_an, rgb_ah_b, rgb_aw_b, rgb_pb);
    pos_bias_kernel<<<(HEADS * AGENT * NPOS + 255) / 256, blk, 0, stream>>>(depth_an, depth_ah_b, depth_aw_b, depth_pb);
    ag_bias_kernel<<<(HEADS * NPOS * AGENT + 255) / 256, blk, 0, stream>>>(rgb_na, rgb_ha_b, rgb_wa_b, rgb_ab);
    ag_bias_kernel<<<(HEADS * NPOS * AGENT + 255) / 256, blk, 0, stream>>>(depth_na, depth_ha_b, depth_wa_b, depth_ab);

    // 4) cross-modal agent aggregation (MFMA flash)
    agent_attn3<<<BATCH * HEADS, blk, 0, stream>>>(depth_ahp, rgb_kv, rgb_pb, depth_agv);
    agent_attn3<<<BATCH * HEADS, blk, 0, stream>>>(rgb_ahp, depth_kv, depth_pb, rgb_agv);

    // 5) agent broadcast (MFMA) + fused depthwise conv (in-place q -> pre)
    q_attn_mfma<<<BATCH * HEADS * 2, blk, 0, stream>>>(rgb_q, rgb_kv, depth_ahp, depth_ab, depth_agv,
                                                       rgb_dwc_w, rgb_dwc_b);
    q_attn_mfma<<<BATCH * HEADS * 2, blk, 0, stream>>>(depth_q, depth_kv, rgb_ahp, rgb_ab, rgb_agv,
                                                       depth_dwc_w, depth_dwc_b);

    // 6) output projections
    float* out = (float*)d_out;
    gemm_mfma<false, true><<<dim3(6, 196), blk, 0, stream>>>(rgb_q, proj_wt_r, rgb_proj_b, out, MROWS, DIM, DIM);
    gemm_mfma<false, true><<<dim3(6, 196), blk, 0, stream>>>(depth_q, proj_wt_d, depth_proj_b,
                                                             out + (size_t)MROWS * DIM, MROWS, DIM, DIM);
}

// Round 8
// 756.369 us; speedup vs baseline: 8.9900x; 1.4899x over previous
//
#include <hip/hip_runtime.h>
#include <hip/hip_bf16.h>

#define BATCH 32
#define NPOS 784
#define DIM 768
#define HEADS 12
#define HD 64
#define AGENT 49
#define HH 28
#define WW 28
#define MROWS (BATCH*NPOS)   // 25088
#define SCALE 0.125f

using bf16 = __hip_bfloat16;
typedef __attribute__((ext_vector_type(4))) float f32x4;
typedef __attribute__((ext_vector_type(8))) short short8v;

__device__ __forceinline__ float bf2f(bf16 x) { return __bfloat162float(x); }
__device__ __forceinline__ float bfs2f(short s) {
    unsigned int u = ((unsigned int)(unsigned short)s) << 16;
    return __uint_as_float(u);
}
__device__ __forceinline__ unsigned short f2bf(float x) {
    unsigned int u = __float_as_uint(x);
    unsigned int r = (u + 0x7fffu + ((u >> 16) & 1u)) >> 16;
    return (unsigned short)r;
}

// async global->LDS, 16B per lane (dest must be wave-uniform base + lane*16)
#define GLOAD_LDS16(g, l) __builtin_amdgcn_global_load_lds( \
    (const __attribute__((address_space(1))) unsigned int*)(g), \
    (__attribute__((address_space(3))) unsigned int*)(l), 16, 0, 0)

// ---------------------------------------------------------------------------
// f32 -> bf16 convert (vectorized): dst[i] = bf16(src[i]), n8 = n/8
// ---------------------------------------------------------------------------
__global__ __launch_bounds__(256) void convert_bf16(
    const float* __restrict__ src, bf16* __restrict__ dst, int n8)
{
    int idx = blockIdx.x * 256 + threadIdx.x;
    if (idx >= n8) return;
    const float* p = src + (size_t)idx * 8;
    float4 r0 = *reinterpret_cast<const float4*>(p);
    float4 r1 = *reinterpret_cast<const float4*>(p + 4);
    short8v v;
    v[0] = (short)f2bf(r0.x); v[1] = (short)f2bf(r0.y);
    v[2] = (short)f2bf(r0.z); v[3] = (short)f2bf(r0.w);
    v[4] = (short)f2bf(r1.x); v[5] = (short)f2bf(r1.y);
    v[6] = (short)f2bf(r1.z); v[7] = (short)f2bf(r1.w);
    *reinterpret_cast<short8v*>((short*)dst + (size_t)idx * 8) = v;
}

// ---------------------------------------------------------------------------
// Transpose+convert: W [K][N] f32 -> Wt [N][K] bf16. 256 thr = 32x8.
// ---------------------------------------------------------------------------
__global__ __launch_bounds__(256) void transpose_w_bf16(
    const float* __restrict__ W, bf16* __restrict__ Wt, int K, int N)
{
    __shared__ float t[32][33];
    int tx = threadIdx.x & 31, ty = threadIdx.x >> 5;
    int k0 = blockIdx.y * 32, n0 = blockIdx.x * 32;
#pragma unroll
    for (int i = 0; i < 4; ++i)
        t[ty + 8 * i][tx] = W[(size_t)(k0 + ty + 8 * i) * N + n0 + tx];
    __syncthreads();
#pragma unroll
    for (int i = 0; i < 4; ++i)
        Wt[(size_t)(n0 + ty + 8 * i) * K + k0 + tx] = __float2bfloat16(t[tx][ty + 8 * i]);
}

// ---------------------------------------------------------------------------
// MFMA GEMM (m97-style): C[M,N] = A[M,K](bf16) @ Bt[N,K](bf16)^T, f32 accum.
// 128x128 tile, BK=64, global_load_lds width-16 both operands.
// LDS linear [128][64], XOR swizzle seg^(row&7) (pre-swizzled source +
// swizzled ds_read) -> 2-way bank aliasing only (free).
// ---------------------------------------------------------------------------
template<bool OUTF32>
__global__ __launch_bounds__(256) void gemm_mfma(
    const bf16* __restrict__ A, const bf16* __restrict__ Bt,
    const float* __restrict__ bias, void* __restrict__ Cp,
    int M, int N, int K)
{
    __shared__ short As[128 * 64];
    __shared__ short Bs[128 * 64];
    int tid = threadIdx.x;
    int wave = tid >> 6, lane = tid & 63;
    int m0 = blockIdx.y * 128, n0 = blockIdx.x * 128;
    int wm = (wave >> 1) * 64, wn = (wave & 1) * 64;
    int acol = lane & 15, kgrp = lane >> 4;

    f32x4 acc[4][4] = {};
    const short* Ab = (const short*)A;
    const short* Btb = (const short*)Bt;

    for (int k0 = 0; k0 < K; k0 += 64) {
#pragma unroll
        for (int it = 0; it < 4; ++it) {
            int idx = tid + 256 * it;          // 1024 chunks of 16B
            int row = idx >> 3, seg = idx & 7;
            int sseg = seg ^ (row & 7);        // pre-swizzled source
            GLOAD_LDS16(Ab + (size_t)(m0 + row) * K + k0 + sseg * 8, &As[idx * 8]);
        }
#pragma unroll
        for (int it = 0; it < 4; ++it) {
            int idx = tid + 256 * it;
            int row = idx >> 3, seg = idx & 7;
            int sseg = seg ^ (row & 7);
            GLOAD_LDS16(Btb + (size_t)(n0 + row) * K + k0 + sseg * 8, &Bs[idx * 8]);
        }
        __syncthreads();

#pragma unroll
        for (int kk = 0; kk < 2; ++kk) {
            short8v af[4], bfr[4];
#pragma unroll
            for (int mf = 0; mf < 4; ++mf) {
                int row = wm + mf * 16 + acol;
                int seg = (kk * 4 + kgrp) ^ (row & 7);
                af[mf] = *reinterpret_cast<const short8v*>(&As[row * 64 + seg * 8]);
            }
#pragma unroll
            for (int nf = 0; nf < 4; ++nf) {
                int row = wn + nf * 16 + acol;
                int seg = (kk * 4 + kgrp) ^ (row & 7);
                bfr[nf] = *reinterpret_cast<const short8v*>(&Bs[row * 64 + seg * 8]);
            }
#pragma unroll
            for (int mf = 0; mf < 4; ++mf)
#pragma unroll
                for (int nf = 0; nf < 4; ++nf)
                    acc[mf][nf] = __builtin_amdgcn_mfma_f32_16x16x32_bf16(
                        af[mf], bfr[nf], acc[mf][nf], 0, 0, 0);
        }
        __syncthreads();
    }

    int rgrp = kgrp * 4;
#pragma unroll
    for (int mf = 0; mf < 4; ++mf)
#pragma unroll
        for (int nf = 0; nf < 4; ++nf)
#pragma unroll
            for (int r = 0; r < 4; ++r) {
                int row = m0 + wm + mf * 16 + rgrp + r;
                int col = n0 + wn + nf * 16 + acol;
                float v = acc[mf][nf][r];
                if constexpr (OUTF32)
                    ((float*)Cp)[(size_t)row * N + col] = v + bias[col];
                else
                    ((bf16*)Cp)[(size_t)row * N + col] = __float2bfloat16(v);
            }
}

// ---------------------------------------------------------------------------
// Pool: ahp[b][a][c] = mean over 4x4 block of q[b][n][c]  (bf16 in, f32 out)
// ---------------------------------------------------------------------------
__global__ void pool_kernel(const bf16* __restrict__ q, float* __restrict__ ahp)
{
    int idx = blockIdx.x * 256 + threadIdx.x;
    if (idx >= BATCH * AGENT * DIM) return;
    int c = idx % DIM;
    int a = (idx / DIM) % AGENT;
    int b = idx / (DIM * AGENT);
    int ai = a / 7, aj = a % 7;
    float s = 0.f;
#pragma unroll
    for (int u = 0; u < 4; ++u)
#pragma unroll
        for (int v = 0; v < 4; ++v) {
            int n = (ai * 4 + u) * WW + (aj * 4 + v);
            s += bf2f(q[((size_t)b * NPOS + n) * DIM + c]);
        }
    ahp[idx] = s * (1.f / 16.f);
}

// ---------------------------------------------------------------------------
// Bilinear 7->28 upsample, half-pixel centers, edge clamp
// ---------------------------------------------------------------------------
__device__ __forceinline__ float bilerp7(const float* __restrict__ img, int i, int j)
{
    float si = 0.25f * i - 0.375f, sj = 0.25f * j - 0.375f;
    int i0 = (int)floorf(si); float fi = si - i0;
    int j0 = (int)floorf(sj); float fj = sj - j0;
    int i0c = min(max(i0, 0), 6), i1c = min(max(i0 + 1, 0), 6);
    int j0c = min(max(j0, 0), 6), j1c = min(max(j0 + 1, 0), 6);
    float v00 = img[i0c * 7 + j0c], v01 = img[i0c * 7 + j1c];
    float v10 = img[i1c * 7 + j0c], v11 = img[i1c * 7 + j1c];
    return (1.f - fi) * ((1.f - fj) * v00 + fj * v01) + fi * ((1.f - fj) * v10 + fj * v11);
}

__global__ void pos_bias_kernel(const float* __restrict__ an, const float* __restrict__ ah_b,
                                const float* __restrict__ aw_b, bf16* __restrict__ pb)
{
    int idx = blockIdx.x * 256 + threadIdx.x;
    if (idx >= HEADS * AGENT * NPOS) return;
    int n = idx % NPOS;
    int a = (idx / NPOS) % AGENT;
    int h = idx / (NPOS * AGENT);
    int i = n / WW, j = n % WW;
    float v = bilerp7(an + (size_t)(h * AGENT + a) * 49, i, j);
    v += ah_b[(h * AGENT + a) * HH + i] + aw_b[(h * AGENT + a) * WW + j];
    pb[idx] = __float2bfloat16(v);
}

__global__ void ag_bias_kernel(const float* __restrict__ na, const float* __restrict__ ha_b,
                               const float* __restrict__ wa_b, bf16* __restrict__ ab)
{
    int idx = blockIdx.x * 256 + threadIdx.x;
    if (idx >= HEADS * NPOS * AGENT) return;
    int a = idx % AGENT;
    int n = (idx / AGENT) % NPOS;
    int h = idx / (AGENT * NPOS);
    int i = n / WW, j = n % WW;
    float v = bilerp7(na + (size_t)(h * AGENT + a) * 49, i, j);
    v += ha_b[(h * HH + i) * AGENT + a] + wa_b[(h * WW + j) * AGENT + a];
    ab[idx] = __float2bfloat16(v);
}

// ---------------------------------------------------------------------------
// Agent attention v3 (full MFMA): one block per (b,h), 4 waves. (unchanged)
// ---------------------------------------------------------------------------
__global__ __launch_bounds__(256, 2) void agent_attn3(
    const float* __restrict__ ahp, const bf16* __restrict__ kv,
    const bf16* __restrict__ pb, bf16* __restrict__ agent_v)
{
    __shared__ __align__(16) char smem[75776];
    short (*pL)[64][72]  = (short (*)[64][72])smem;            // [4][64][72]
    short (*VtL)[64][72] = (short (*)[64][72])(smem + 36864);  // [4][64][72]
    float (*Om)[64][66]  = (float (*)[64][66])smem;            // aliases pL/VtL
    float (*mw)[64]      = (float (*)[64])(smem + 73728);
    float (*lw)[64]      = (float (*)[64])(smem + 74752);

    int tid = threadIdx.x;
    int wave = tid >> 6, lane = tid & 63;
    int acol = lane & 15, kgrp = lane >> 4;
    int h = blockIdx.x % HEADS;
    int b = blockIdx.x / HEADS;
    const short* kvs = (const short*)kv;
    const bf16* pbh = pb + (size_t)h * AGENT * NPOS;

    short8v qa[2][4];
#pragma unroll
    for (int ks = 0; ks < 2; ++ks)
#pragma unroll
        for (int mf = 0; mf < 4; ++mf) {
            int a = mf * 16 + acol;
            short8v v = {};
            if (a < AGENT) {
                const float* src = ahp + ((size_t)b * AGENT + a) * DIM + h * HD + ks * 32 + kgrp * 8;
                float4 r0 = *reinterpret_cast<const float4*>(src);
                float4 r1 = *reinterpret_cast<const float4*>(src + 4);
                v[0] = (short)f2bf(r0.x * SCALE); v[1] = (short)f2bf(r0.y * SCALE);
                v[2] = (short)f2bf(r0.z * SCALE); v[3] = (short)f2bf(r0.w * SCALE);
                v[4] = (short)f2bf(r1.x * SCALE); v[5] = (short)f2bf(r1.y * SCALE);
                v[6] = (short)f2bf(r1.z * SCALE); v[7] = (short)f2bf(r1.w * SCALE);
            }
            qa[ks][mf] = v;
        }

    float mrun[16], lrun[16];
#pragma unroll
    for (int i = 0; i < 16; ++i) { mrun[i] = -1e30f; lrun[i] = 0.f; }
    f32x4 accO[4][4] = {};

    for (int t = wave; t < 13; t += 4) {
        int n0 = t * 64;
        {
            int p = lane & 31, dh = lane >> 5;
            const short* v0p = kvs + (size_t)(b * NPOS + n0 + 2 * p) * (2 * DIM) + DIM + h * HD + dh * 32;
#pragma unroll
            for (int s = 0; s < 4; ++s) {
                short8v va = {}, vb = {};
                if (n0 + 2 * p < NPOS)     va = *reinterpret_cast<const short8v*>(v0p + s * 8);
                if (n0 + 2 * p + 1 < NPOS) vb = *reinterpret_cast<const short8v*>(v0p + 2 * DIM + s * 8);
#pragma unroll
                for (int u = 0; u < 8; ++u) {
                    int d = dh * 32 + s * 8 + u;
                    unsigned int w = ((unsigned int)(unsigned short)va[u]) |
                                     (((unsigned int)(unsigned short)vb[u]) << 16);
                    *reinterpret_cast<unsigned int*>(&VtL[wave][d][2 * p]) = w;
                }
            }
        }

        short8v kb[2][4];
#pragma unroll
        for (int nf = 0; nf < 4; ++nf) {
            int n = n0 + nf * 16 + acol;
            bool val = (n < NPOS);
            const short* kp = kvs + (size_t)(b * NPOS + n) * (2 * DIM) + h * HD + kgrp * 8;
#pragma unroll
            for (int ks = 0; ks < 2; ++ks) {
                short8v v = {};
                if (val) v = *reinterpret_cast<const short8v*>(kp + ks * 32);
                kb[ks][nf] = v;
            }
        }

        f32x4 accS[4][4] = {};
#pragma unroll
        for (int mf = 0; mf < 4; ++mf)
#pragma unroll
            for (int nf = 0; nf < 4; ++nf) {
                accS[mf][nf] = __builtin_amdgcn_mfma_f32_16x16x32_bf16(qa[0][mf], kb[0][nf], accS[mf][nf], 0, 0, 0);
                accS[mf][nf] = __builtin_amdgcn_mfma_f32_16x16x32_bf16(qa[1][mf], kb[1][nf], accS[mf][nf], 0, 0, 0);
            }

#pragma unroll
        for (int mf = 0; mf < 4; ++mf)
#pragma unroll
            for (int r = 0; r < 4; ++r) {
                int a = mf * 16 + kgrp * 4 + r;
                float s[4];
                float mt = -1e30f;
#pragma unroll
                for (int nf = 0; nf < 4; ++nf) {
                    int n = n0 + nf * 16 + acol;
                    float sv = -1e30f;
                    if (n < NPOS) {
                        sv = accS[mf][nf][r];
                        if (a < AGENT) sv += bf2f(pbh[(size_t)a * NPOS + n]);
                    }
                    s[nf] = sv;
                    mt = fmaxf(mt, sv);
                }
#pragma unroll
                for (int off = 1; off < 16; off <<= 1)
                    mt = fmaxf(mt, __shfl_xor(mt, off));
                float mnew = fmaxf(mrun[mf * 4 + r], mt);
                float fac = __expf(mrun[mf * 4 + r] - mnew);
                float ps = 0.f;
#pragma unroll
                for (int nf = 0; nf < 4; ++nf) {
                    float pv = (s[nf] > -1e29f) ? __expf(s[nf] - mnew) : 0.f;
                    ps += pv;
                    pL[wave][a][nf * 16 + acol] = (short)f2bf(pv);
                }
#pragma unroll
                for (int off = 1; off < 16; off <<= 1)
                    ps += __shfl_xor(ps, off);
                mrun[mf * 4 + r] = mnew;
                lrun[mf * 4 + r] = lrun[mf * 4 + r] * fac + ps;
#pragma unroll
                for (int df = 0; df < 4; ++df) accO[mf][df][r] *= fac;
            }

        short8v vb2[2][4];
#pragma unroll
        for (int ks = 0; ks < 2; ++ks)
#pragma unroll
            for (int df = 0; df < 4; ++df)
                vb2[ks][df] = *reinterpret_cast<const short8v*>(
                    &VtL[wave][df * 16 + acol][ks * 32 + kgrp * 8]);
#pragma unroll
        for (int mf = 0; mf < 4; ++mf) {
#pragma unroll
            for (int ks = 0; ks < 2; ++ks) {
                short8v pa = *reinterpret_cast<const short8v*>(
                    &pL[wave][mf * 16 + acol][ks * 32 + kgrp * 8]);
#pragma unroll
                for (int df = 0; df < 4; ++df)
                    accO[mf][df] = __builtin_amdgcn_mfma_f32_16x16x32_bf16(pa, vb2[ks][df], accO[mf][df], 0, 0, 0);
            }
        }
    }

    if (acol == 0) {
#pragma unroll
        for (int mf = 0; mf < 4; ++mf)
#pragma unroll
            for (int r = 0; r < 4; ++r) {
                mw[wave][mf * 16 + kgrp * 4 + r] = mrun[mf * 4 + r];
                lw[wave][mf * 16 + kgrp * 4 + r] = lrun[mf * 4 + r];
            }
    }
    __syncthreads();
#pragma unroll
    for (int mf = 0; mf < 4; ++mf)
#pragma unroll
        for (int df = 0; df < 4; ++df)
#pragma unroll
            for (int r = 0; r < 4; ++r)
                Om[wave][mf * 16 + kgrp * 4 + r][df * 16 + acol] = accO[mf][df][r];
    __syncthreads();

    for (int idx = tid; idx < AGENT * HD; idx += 256) {
        int a = idx >> 6, d = idx & 63;
        float m = fmaxf(fmaxf(mw[0][a], mw[1][a]), fmaxf(mw[2][a], mw[3][a]));
        float l = 0.f, o = 0.f;
#pragma unroll
        for (int w = 0; w < 4; ++w) {
            float f = __expf(mw[w][a] - m);
            l += f * lw[w][a];
            o += f * Om[w][a][d];
        }
        ((short*)agent_v)[(((size_t)b * HEADS + h) * AGENT + a) * HD + d] = (short)f2bf(o / l);
    }
}

// ---------------------------------------------------------------------------
// Q attention via MFMA + fused depthwise conv (vectorized), IN-PLACE over q.
// Attention output staged to per-wave oL[16][68] f32; conv phase re-maps
// lanes to (row, d8) and uses short8v 16B loads of V + LDS weights.
// ---------------------------------------------------------------------------
__global__ __launch_bounds__(256) void q_attn_mfma(
    bf16* qpre, const bf16* __restrict__ kv_own,
    const float* __restrict__ ahp_x, const bf16* __restrict__ ab_x,
    const bf16* __restrict__ agv_x,
    const float* __restrict__ dwc_w, const float* __restrict__ dwc_b)
{
    __shared__ short pL[4][16][72];
    __shared__ float oL[4][16][68];
    __shared__ float wS[9][64];
    __shared__ float cbS[64];

    int blk = blockIdx.x;
    int half = blk & 1;
    int h = (blk >> 1) % HEADS;
    int b = blk / (2 * HEADS);
    int tid = threadIdx.x;
    int wave = tid >> 6, lane = tid & 63;
    int acol = lane & 15, kgrp = lane >> 4;

    for (int i = tid; i < 9 * 64; i += 256)
        wS[i >> 6][i & 63] = dwc_w[(i >> 6) * DIM + h * HD + (i & 63)];
    if (tid < 64) cbS[tid] = dwc_b[h * HD + tid];
    for (int i = tid; i < 4 * 16 * 72; i += 256)
        ((short*)pL)[i] = 0;

    short8v bs[2][4];
#pragma unroll
    for (int ks = 0; ks < 2; ++ks)
#pragma unroll
        for (int nf = 0; nf < 4; ++nf) {
            int a = nf * 16 + acol;
            short8v v = {};
            if (a < AGENT) {
                const float* src = ahp_x + ((size_t)b * AGENT + a) * DIM + h * HD + ks * 32 + kgrp * 8;
                float4 r0 = *reinterpret_cast<const float4*>(src);
                float4 r1 = *reinterpret_cast<const float4*>(src + 4);
                v[0] = (short)f2bf(r0.x * SCALE); v[1] = (short)f2bf(r0.y * SCALE);
                v[2] = (short)f2bf(r0.z * SCALE); v[3] = (short)f2bf(r0.w * SCALE);
                v[4] = (short)f2bf(r1.x * SCALE); v[5] = (short)f2bf(r1.y * SCALE);
                v[6] = (short)f2bf(r1.z * SCALE); v[7] = (short)f2bf(r1.w * SCALE);
            }
            bs[ks][nf] = v;
        }

    const short* agvs = (const short*)agv_x;
    short8v bv[2][4];
#pragma unroll
    for (int ks = 0; ks < 2; ++ks)
#pragma unroll
        for (int nf = 0; nf < 4; ++nf) {
            int d = nf * 16 + acol;
            short8v v = {};
#pragma unroll
            for (int i = 0; i < 8; ++i) {
                int a = ks * 32 + kgrp * 8 + i;
                if (a < AGENT)
                    v[i] = agvs[(((size_t)b * HEADS + h) * AGENT + a) * HD + d];
            }
            bv[ks][nf] = v;
        }

    __syncthreads();

    int tstart = half ? 25 : 0, tend = half ? 49 : 25;
    for (int t = tstart + wave; t < tend; t += 4) {
        int n0 = t * 16;
        const short* qrow = (const short*)qpre +
            ((size_t)(b * NPOS + n0 + acol)) * DIM + h * HD + kgrp * 8;
        short8v a0 = *reinterpret_cast<const short8v*>(qrow);
        short8v a1 = *reinterpret_cast<const short8v*>(qrow + 32);

        f32x4 accs[4] = {};
#pragma unroll
        for (int nf = 0; nf < 4; ++nf) {
            accs[nf] = __builtin_amdgcn_mfma_f32_16x16x32_bf16(a0, bs[0][nf], accs[nf], 0, 0, 0);
            accs[nf] = __builtin_amdgcn_mfma_f32_16x16x32_bf16(a1, bs[1][nf], accs[nf], 0, 0, 0);
        }

        float inv[4];
#pragma unroll
        for (int r = 0; r < 4; ++r) {
            int n = n0 + kgrp * 4 + r;
            float sarr[4];
            float m = -1e30f;
#pragma unroll
            for (int nf = 0; nf < 4; ++nf) {
                int a = nf * 16 + acol;
                float s = -1e30f;
                if (a < AGENT)
                    s = accs[nf][r] + bf2f(ab_x[((size_t)h * NPOS + n) * AGENT + a]);
                sarr[nf] = s;
                m = fmaxf(m, s);
            }
#pragma unroll
            for (int off = 1; off < 16; off <<= 1)
                m = fmaxf(m, __shfl_xor(m, off));
            float ls = 0.f;
#pragma unroll
            for (int nf = 0; nf < 4; ++nf) {
                float p = (sarr[nf] > -1e29f) ? __expf(sarr[nf] - m) : 0.f;
                sarr[nf] = p;
                ls += p;
            }
#pragma unroll
            for (int off = 1; off < 16; off <<= 1)
                ls += __shfl_xor(ls, off);
            inv[r] = 1.f / ls;
#pragma unroll
            for (int nf = 0; nf < 4; ++nf) {
                int a = nf * 16 + acol;
                if (a < AGENT)
                    pL[wave][kgrp * 4 + r][a] = (short)f2bf(sarr[nf]);
            }
        }

        short8v p0 = *reinterpret_cast<const short8v*>(&pL[wave][acol][kgrp * 8]);
        short8v p1 = *reinterpret_cast<const short8v*>(&pL[wave][acol][kgrp * 8 + 32]);

        f32x4 acco[4] = {};
#pragma unroll
        for (int nf = 0; nf < 4; ++nf) {
            acco[nf] = __builtin_amdgcn_mfma_f32_16x16x32_bf16(p0, bv[0][nf], acco[nf], 0, 0, 0);
            acco[nf] = __builtin_amdgcn_mfma_f32_16x16x32_bf16(p1, bv[1][nf], acco[nf], 0, 0, 0);
        }

        // stage attention output to oL (wave-private)
#pragma unroll
        for (int r = 0; r < 4; ++r)
#pragma unroll
            for (int nf = 0; nf < 4; ++nf)
                oL[wave][kgrp * 4 + r][nf * 16 + acol] = acco[nf][r] * inv[r];

        // conv phase: lane -> (row, d8); short8v V loads + LDS weights
#pragma unroll
        for (int it2 = 0; it2 < 2; ++it2) {
            int item = lane + 64 * it2;       // 0..127
            int rl = item >> 3, d8 = item & 7;
            int n = n0 + rl;
            int i = n / WW, j = n % WW;
            float accv[8];
            {
                float4 o0 = *reinterpret_cast<const float4*>(&oL[wave][rl][d8 * 8]);
                float4 o1 = *reinterpret_cast<const float4*>(&oL[wave][rl][d8 * 8 + 4]);
                accv[0] = o0.x + cbS[d8 * 8 + 0]; accv[1] = o0.y + cbS[d8 * 8 + 1];
                accv[2] = o0.z + cbS[d8 * 8 + 2]; accv[3] = o0.w + cbS[d8 * 8 + 3];
                accv[4] = o1.x + cbS[d8 * 8 + 4]; accv[5] = o1.y + cbS[d8 * 8 + 5];
                accv[6] = o1.z + cbS[d8 * 8 + 6]; accv[7] = o1.w + cbS[d8 * 8 + 7];
            }
#pragma unroll
            for (int di = -1; di <= 1; ++di) {
                int ii = i + di;
                if (ii < 0 || ii >= HH) continue;
#pragma unroll
                for (int dj = -1; dj <= 1; ++dj) {
                    int jj = j + dj;
                    if (jj < 0 || jj >= WW) continue;
                    short8v vv = *reinterpret_cast<const short8v*>(
                        (const short*)kv_own + ((size_t)(b * NPOS + ii * WW + jj)) * (2 * DIM) + DIM + h * HD + d8 * 8);
                    int tap = (di + 1) * 3 + (dj + 1);
#pragma unroll
                    for (int u = 0; u < 8; ++u)
                        accv[u] += wS[tap][d8 * 8 + u] * bfs2f(vv[u]);
                }
            }
            short8v ov;
#pragma unroll
            for (int u = 0; u < 8; ++u) ov[u] = (short)f2bf(accv[u]);
            *reinterpret_cast<short8v*>((short*)qpre +
                ((size_t)(b * NPOS + n)) * DIM + h * HD + d8 * 8) = ov;
        }
    }
}

// ---------------------------------------------------------------------------
extern "C" void kernel_launch(void* const* d_in, const int* in_sizes, int n_in,
                              void* d_out, int out_size, void* d_ws, size_t ws_size,
                              hipStream_t stream)
{
    const float* rgb_fea    = (const float*)d_in[0];
    const float* depth_fea  = (const float*)d_in[1];
    const float* rgb_q_w    = (const float*)d_in[2];
    const float* rgb_kv_w   = (const float*)d_in[3];
    const float* rgb_proj_w = (const float*)d_in[4];
    const float* rgb_proj_b = (const float*)d_in[5];
    const float* depth_q_w    = (const float*)d_in[6];
    const float* depth_kv_w   = (const float*)d_in[7];
    const float* depth_proj_w = (const float*)d_in[8];
    const float* depth_proj_b = (const float*)d_in[9];
    const float* rgb_dwc_w   = (const float*)d_in[10];
    const float* rgb_dwc_b   = (const float*)d_in[11];
    const float* depth_dwc_w = (const float*)d_in[12];
    const float* depth_dwc_b = (const float*)d_in[13];
    const float* rgb_an   = (const float*)d_in[14];
    const float* rgb_na   = (const float*)d_in[15];
    const float* rgb_ah_b = (const float*)d_in[16];
    const float* rgb_aw_b = (const float*)d_in[17];
    const float* rgb_ha_b = (const float*)d_in[18];
    const float* rgb_wa_b = (const float*)d_in[19];
    const float* depth_an   = (const float*)d_in[20];
    const float* depth_na   = (const float*)d_in[21];
    const float* depth_ah_b = (const float*)d_in[22];
    const float* depth_aw_b = (const float*)d_in[23];
    const float* depth_ha_b = (const float*)d_in[24];
    const float* depth_wa_b = (const float*)d_in[25];

    char* ws = (char*)d_ws;
    size_t off = 0;
    auto alloc = [&](size_t bytes) -> void* {
        void* p = ws + off;
        off += (bytes + 255) & ~(size_t)255;
        return p;
    };
    bf16* rgb_q    = (bf16*)alloc((size_t)MROWS * DIM * 2);
    bf16* depth_q  = (bf16*)alloc((size_t)MROWS * DIM * 2);
    bf16* rgb_kv   = (bf16*)alloc((size_t)MROWS * 2 * DIM * 2);
    bf16* depth_kv = (bf16*)alloc((size_t)MROWS * 2 * DIM * 2);
    bf16* rgb_pb    = (bf16*)alloc((size_t)HEADS * AGENT * NPOS * 2);
    bf16* depth_pb  = (bf16*)alloc((size_t)HEADS * AGENT * NPOS * 2);
    bf16* rgb_ab    = (bf16*)alloc((size_t)HEADS * NPOS * AGENT * 2);
    bf16* depth_ab  = (bf16*)alloc((size_t)HEADS * NPOS * AGENT * 2);
    bf16* rgb_agv   = (bf16*)alloc((size_t)BATCH * HEADS * AGENT * HD * 2);
    bf16* depth_agv = (bf16*)alloc((size_t)BATCH * HEADS * AGENT * HD * 2);
    bf16* proj_wt_r = (bf16*)alloc((size_t)DIM * DIM * 2);
    bf16* proj_wt_d = (bf16*)alloc((size_t)DIM * DIM * 2);
    size_t ubase = off;
    bf16* q_wt_r  = (bf16*)alloc((size_t)DIM * DIM * 2);
    bf16* kv_wt_r = (bf16*)alloc((size_t)DIM * 2 * DIM * 2);
    bf16* q_wt_d  = (bf16*)alloc((size_t)DIM * DIM * 2);
    bf16* kv_wt_d = (bf16*)alloc((size_t)DIM * 2 * DIM * 2);
    off = ubase;  // alias
    float* rgb_ahp   = (float*)alloc((size_t)BATCH * AGENT * DIM * 4);
    float* depth_ahp = (float*)alloc((size_t)BATCH * AGENT * DIM * 4);

    // d_out doubles as scratch for the bf16-converted activations
    // (dead before the proj GEMMs overwrite d_out with final results)
    bf16* fea_bf_r = (bf16*)d_out;
    bf16* fea_bf_d = fea_bf_r + (size_t)MROWS * DIM;

    dim3 blk(256);
    int n8 = MROWS * DIM / 8;

    // 0) activation f32->bf16 + weight transposes
    convert_bf16<<<(n8 + 255) / 256, blk, 0, stream>>>(rgb_fea, fea_bf_r, n8);
    convert_bf16<<<(n8 + 255) / 256, blk, 0, stream>>>(depth_fea, fea_bf_d, n8);
    transpose_w_bf16<<<dim3(24, 24), blk, 0, stream>>>(rgb_q_w, q_wt_r, DIM, DIM);
    transpose_w_bf16<<<dim3(48, 24), blk, 0, stream>>>(rgb_kv_w, kv_wt_r, DIM, 2 * DIM);
    transpose_w_bf16<<<dim3(24, 24), blk, 0, stream>>>(depth_q_w, q_wt_d, DIM, DIM);
    transpose_w_bf16<<<dim3(48, 24), blk, 0, stream>>>(depth_kv_w, kv_wt_d, DIM, 2 * DIM);
    transpose_w_bf16<<<dim3(24, 24), blk, 0, stream>>>(rgb_proj_w, proj_wt_r, DIM, DIM);
    transpose_w_bf16<<<dim3(24, 24), blk, 0, stream>>>(depth_proj_w, proj_wt_d, DIM, DIM);

    // 1) q / kv projections (pure bf16 MFMA, global_load_lds staging)
    gemm_mfma<false><<<dim3(6, 196), blk, 0, stream>>>(fea_bf_r, q_wt_r, nullptr, rgb_q, MROWS, DIM, DIM);
    gemm_mfma<false><<<dim3(6, 196), blk, 0, stream>>>(fea_bf_d, q_wt_d, nullptr, depth_q, MROWS, DIM, DIM);
    gemm_mfma<false><<<dim3(12, 196), blk, 0, stream>>>(fea_bf_r, kv_wt_r, nullptr, rgb_kv, MROWS, 2 * DIM, DIM);
    gemm_mfma<false><<<dim3(12, 196), blk, 0, stream>>>(fea_bf_d, kv_wt_d, nullptr, depth_kv, MROWS, 2 * DIM, DIM);

    // 2) agent pooling of q
    pool_kernel<<<(BATCH * AGENT * DIM + 255) / 256, blk, 0, stream>>>(rgb_q, rgb_ahp);
    pool_kernel<<<(BATCH * AGENT * DIM + 255) / 256, blk, 0, stream>>>(depth_q, depth_ahp);

    // 3) position biases
    pos_bias_kernel<<<(HEADS * AGENT * NPOS + 255) / 256, blk, 0, stream>>>(rgb_an, rgb_ah_b, rgb_aw_b, rgb_pb);
    pos_bias_kernel<<<(HEADS * AGENT * NPOS + 255) / 256, blk, 0, stream>>>(depth_an, depth_ah_b, depth_aw_b, depth_pb);
    ag_bias_kernel<<<(HEADS * NPOS * AGENT + 255) / 256, blk, 0, stream>>>(rgb_na, rgb_ha_b, rgb_wa_b, rgb_ab);
    ag_bias_kernel<<<(HEADS * NPOS * AGENT + 255) / 256, blk, 0, stream>>>(depth_na, depth_ha_b, depth_wa_b, depth_ab);

    // 4) cross-modal agent aggregation (MFMA flash)
    agent_attn3<<<BATCH * HEADS, blk, 0, stream>>>(depth_ahp, rgb_kv, rgb_pb, depth_agv);
    agent_attn3<<<BATCH * HEADS, blk, 0, stream>>>(rgb_ahp, depth_kv, depth_pb, rgb_agv);

    // 5) agent broadcast (MFMA) + fused vectorized depthwise conv
    q_attn_mfma<<<BATCH * HEADS * 2, blk, 0, stream>>>(rgb_q, rgb_kv, depth_ahp, depth_ab, depth_agv,
                                                       rgb_dwc_w, rgb_dwc_b);
    q_attn_mfma<<<BATCH * HEADS * 2, blk, 0, stream>>>(depth_q, depth_kv, rgb_ahp, rgb_ab, rgb_agv,
                                                       depth_dwc_w, depth_dwc_b);

    // 6) output projections (overwrite d_out scratch with final results)
    float* out = (float*)d_out;
    gemm_mfma<true><<<dim3(6, 196), blk, 0, stream>>>(rgb_q, proj_wt_r, rgb_proj_b, out, MROWS, DIM, DIM);
    gemm_mfma<true><<<dim3(6, 196), blk, 0, stream>>>(depth_q, proj_wt_d, depth_proj_b,
                                                      out + (size_t)MROWS * DIM, MROWS, DIM, DIM);
}